// Round 2
// baseline (3090.659 us; speedup 1.0000x reference)
//
#include <hip/hip_runtime.h>
#include <math.h>

// LSTM: I=5, H=64, L=3, O=1, B=1024, T=256, fp32.
// Round-5 resubmit (round-1 bench failed: GPUAcquisitionTimeout, no data).
// r4 structure + three VALU-count cuts (r4 was 63% VALUBusy, 0% MFMA,
// 0.03% HBM -> pure vector-issue + serial-stall bound):
//  (a) chained fmaf dot products (was mul+add trees, ~48 ops/32 MACs -> 32)
//  (b) cheap activations via v_rcp/v_exp (was full-precision fp32 div ~10 ops)
//      + dedup: lane s activates only batch elem s (was 2x redundant)
//      + single shfl_xor via operand cross-select (was 2 shfls)
//  (c) software-pipeline the input-half GEMM: ain(tt+1) (reads only chunk
//      buffers h0c/h1c/xs, which are final) is computed in the combine window
//      between the two barriers, so the post-barrier critical path is REC-only.
// Structure unchanged: 512 blocks x 512 thr, TB=2 batch/block, k-split s=tid&1
// (32 weights/half), gate row g=tid>>1, weights in NAMED float4 registers,
// asm memory barriers to prevent weight-load hoisting (anti-spill, see r1/r2).
// __launch_bounds__(512,4): 4 waves/EU -> VGPR cap 128, protects 2 blocks/CU.

constexpr int Hh = 64;
constexpr int G4 = 256;   // 4*H gate rows
constexpr int Tt = 256;   // timesteps
constexpr int In = 5;     // input size
constexpr int TB = 2;     // batch elems per block
constexpr int TC = 64;    // timestep chunk
constexpr int NB = 512;   // blocks (NB*TB = 1024 = B)
constexpr int NT = 512;   // threads per block

// fast activations: v_mul + v_exp + v_add + v_rcp (+ v_fma for tanh)
__device__ __forceinline__ float sigm(float x) {
    return __builtin_amdgcn_rcpf(1.0f + exp2f(-1.442695041f * x));
}
__device__ __forceinline__ float tanhc(float x) {
    // tanh(x) = 2*sigmoid(2x) - 1; saturates correctly at +/-inf, NaN-free
    return fmaf(2.0f, __builtin_amdgcn_rcpf(1.0f + exp2f(-2.885390082f * x)), -1.0f);
}

#define FMA4(acc, W, H) do { \
    acc = fmaf((W).x, (H).x, acc); acc = fmaf((W).y, (H).y, acc); \
    acc = fmaf((W).z, (H).z, acc); acc = fmaf((W).w, (H).w, acc); } while (0)

// macros reference wh0..wh7 / wi0..wi7 named float4s from enclosing scope
#define REC32(acc, HPTR) do { \
    const float4* hp_ = reinterpret_cast<const float4*>(HPTR); \
    float4 hA=hp_[0], hB=hp_[1], hC=hp_[2], hD=hp_[3]; \
    float4 hE=hp_[4], hF=hp_[5], hG=hp_[6], hH=hp_[7]; \
    FMA4(acc,wh0,hA); FMA4(acc,wh1,hB); FMA4(acc,wh2,hC); FMA4(acc,wh3,hD); \
    FMA4(acc,wh4,hE); FMA4(acc,wh5,hF); FMA4(acc,wh6,hG); FMA4(acc,wh7,hH); \
} while (0)

#define IN32(acc, HPTR) do { \
    const float4* ip_ = reinterpret_cast<const float4*>(HPTR); \
    float4 iA=ip_[0], iB=ip_[1], iC=ip_[2], iD=ip_[3]; \
    float4 iE=ip_[4], iF=ip_[5], iG=ip_[6], iH=ip_[7]; \
    FMA4(acc,wi0,iA); FMA4(acc,wi1,iB); FMA4(acc,wi2,iC); FMA4(acc,wi3,iD); \
    FMA4(acc,wi4,iE); FMA4(acc,wi5,iF); FMA4(acc,wi6,iG); FMA4(acc,wi7,iH); \
} while (0)

__global__ __launch_bounds__(NT, 4) void lstm3_fused(
    const float* __restrict__ x,
    const float* __restrict__ w_ih0, const float* __restrict__ w_hh0,
    const float* __restrict__ b_ih0, const float* __restrict__ b_hh0,
    const float* __restrict__ w_ih1, const float* __restrict__ w_hh1,
    const float* __restrict__ b_ih1, const float* __restrict__ b_hh1,
    const float* __restrict__ w_ih2, const float* __restrict__ w_hh2,
    const float* __restrict__ b_ih2, const float* __restrict__ b_hh2,
    const float* __restrict__ w_fc,  const float* __restrict__ b_fc,
    float* __restrict__ out, int nch)
{
    __shared__ alignas(16) float h0c[TB][TC][Hh];   // layer0 output chunk (32 KB)
    __shared__ alignas(16) float h1c[TB][TC][Hh];   // layer1 output chunk (32 KB)
    __shared__ alignas(16) float hst[3][TB][Hh];    // recurrent h state per layer
    __shared__ alignas(16) float gbuf[TB][G4];      // activated gates
    __shared__ alignas(16) float xs[TB][TC][In];    // staged input chunk

    const int tid = threadIdx.x;
    const int g   = tid >> 1;         // gate row 0..255
    const int s   = tid & 1;          // k-half 0..1
    const int gt  = tid >> 7;         // 0:i 1:f 2:g~ 3:o (wave-uniform)
    const int b0  = blockIdx.x * TB;
    const int cu  = tid & (Hh - 1);   // combine: hidden unit (tid < 128)
    const int cb  = tid >> 6;         // combine: batch elem

    float c0s = 0.f, c1s = 0.f, c2s = 0.f;   // c state (threads tid < TB*Hh)

    for (int i = tid; i < 3 * TB * Hh; i += NT) ((float*)hst)[i] = 0.f;

    #pragma unroll 1
    for (int chunk = 0; chunk < nch; ++chunk) {
        const int t0 = chunk * TC;

        // ---- stage x chunk (tiny: 640 floats) ----
        for (int i = tid; i < TB * TC * In; i += NT) {
            int b  = i / (TC * In);
            int r  = i - b * (TC * In);
            int t  = r / In;
            int cc = r - t * In;
            xs[b][t][cc] = x[((size_t)(b0 + b) * Tt + (t0 + t)) * In + cc];
        }

        // ================= layer 0 =================
        {
            asm volatile("" ::: "memory");   // block hoist of weight loads
            float wiA0=0.f, wiA1=0.f, wiA2=0.f, wiA3=0.f, wiA4=0.f, bias=0.f;
            if (s == 0) {
                wiA0 = w_ih0[g*In+0]; wiA1 = w_ih0[g*In+1]; wiA2 = w_ih0[g*In+2];
                wiA3 = w_ih0[g*In+3]; wiA4 = w_ih0[g*In+4];
                bias = b_ih0[g] + b_hh0[g];
            }
            const float4* w4 = reinterpret_cast<const float4*>(w_hh0 + g * Hh + 32 * s);
            float4 wh0=w4[0], wh1=w4[1], wh2=w4[2], wh3=w4[3];
            float4 wh4=w4[4], wh5=w4[5], wh6=w4[6], wh7=w4[7];
            __syncthreads();   // xs staged (+ chunk 0: hst zero-init visible)

            // prefetch input-half for tt=0 (s==1 lanes compute 0: weights are 0)
            float ain0 = fmaf(wiA4, xs[0][0][4], fmaf(wiA3, xs[0][0][3],
                         fmaf(wiA2, xs[0][0][2], fmaf(wiA1, xs[0][0][1],
                         fmaf(wiA0, xs[0][0][0], bias)))));
            float ain1 = fmaf(wiA4, xs[1][0][4], fmaf(wiA3, xs[1][0][3],
                         fmaf(wiA2, xs[1][0][2], fmaf(wiA1, xs[1][0][1],
                         fmaf(wiA0, xs[1][0][0], bias)))));

            #pragma unroll 1
            for (int tt = 0; tt < TC; ++tt) {
                float a0 = ain0; REC32(a0, &hst[0][0][32*s]);
                float a1 = ain1; REC32(a1, &hst[0][1][32*s]);
                // single shuffle: keep own elem's partial, send partner's
                float keep = s ? a1 : a0;
                float send = s ? a0 : a1;
                float v  = keep + __shfl_xor(send, 1, 64);
                float av = (gt == 2) ? tanhc(v) : sigm(v);
                gbuf[s][g] = av;
                __syncthreads();
                if (tid < TB * Hh) {
                    float iv = gbuf[cb][cu];
                    float fv = gbuf[cb][Hh + cu];
                    float gv = gbuf[cb][2*Hh + cu];
                    float ov = gbuf[cb][3*Hh + cu];
                    float c_ = fmaf(fv, c0s, iv * gv);
                    c0s = c_;
                    float hn = ov * tanhc(c_);
                    hst[0][cb][cu] = hn;
                    h0c[cb][tt][cu] = hn;
                }
                if (tt + 1 < TC) {   // overlap next input-half with combine
                    ain0 = fmaf(wiA4, xs[0][tt+1][4], fmaf(wiA3, xs[0][tt+1][3],
                           fmaf(wiA2, xs[0][tt+1][2], fmaf(wiA1, xs[0][tt+1][1],
                           fmaf(wiA0, xs[0][tt+1][0], bias)))));
                    ain1 = fmaf(wiA4, xs[1][tt+1][4], fmaf(wiA3, xs[1][tt+1][3],
                           fmaf(wiA2, xs[1][tt+1][2], fmaf(wiA1, xs[1][tt+1][1],
                           fmaf(wiA0, xs[1][tt+1][0], bias)))));
                }
                __syncthreads();
            }
        }

        // ================= layer 1 =================
        {
            asm volatile("" ::: "memory");
            const float4* wi4p = reinterpret_cast<const float4*>(w_ih1 + g * Hh + 32 * s);
            float4 wi0=wi4p[0], wi1=wi4p[1], wi2=wi4p[2], wi3=wi4p[3];
            float4 wi4=wi4p[4], wi5=wi4p[5], wi6=wi4p[6], wi7=wi4p[7];
            const float4* wh4p = reinterpret_cast<const float4*>(w_hh1 + g * Hh + 32 * s);
            float4 wh0=wh4p[0], wh1=wh4p[1], wh2=wh4p[2], wh3=wh4p[3];
            float4 wh4=wh4p[4], wh5=wh4p[5], wh6=wh4p[6], wh7=wh4p[7];
            float bias = (s == 0) ? (b_ih1[g] + b_hh1[g]) : 0.f;
            // h0c fully written (final barrier of layer-0 loop)

            float ain0 = bias; IN32(ain0, &h0c[0][0][32*s]);
            float ain1 = bias; IN32(ain1, &h0c[1][0][32*s]);

            #pragma unroll 1
            for (int tt = 0; tt < TC; ++tt) {
                float a0 = ain0; REC32(a0, &hst[1][0][32*s]);
                float a1 = ain1; REC32(a1, &hst[1][1][32*s]);
                float keep = s ? a1 : a0;
                float send = s ? a0 : a1;
                float v  = keep + __shfl_xor(send, 1, 64);
                float av = (gt == 2) ? tanhc(v) : sigm(v);
                gbuf[s][g] = av;
                __syncthreads();
                if (tid < TB * Hh) {
                    float iv = gbuf[cb][cu];
                    float fv = gbuf[cb][Hh + cu];
                    float gv = gbuf[cb][2*Hh + cu];
                    float ov = gbuf[cb][3*Hh + cu];
                    float c_ = fmaf(fv, c1s, iv * gv);
                    c1s = c_;
                    float hn = ov * tanhc(c_);
                    hst[1][cb][cu] = hn;
                    h1c[cb][tt][cu] = hn;
                }
                if (tt + 1 < TC) {   // overlap next input-half with combine
                    ain0 = bias; IN32(ain0, &h0c[0][tt+1][32*s]);
                    ain1 = bias; IN32(ain1, &h0c[1][tt+1][32*s]);
                }
                __syncthreads();
            }
        }

        // ================= layer 2 =================
        {
            asm volatile("" ::: "memory");
            const float4* wi4p = reinterpret_cast<const float4*>(w_ih2 + g * Hh + 32 * s);
            float4 wi0=wi4p[0], wi1=wi4p[1], wi2=wi4p[2], wi3=wi4p[3];
            float4 wi4=wi4p[4], wi5=wi4p[5], wi6=wi4p[6], wi7=wi4p[7];
            const float4* wh4p = reinterpret_cast<const float4*>(w_hh2 + g * Hh + 32 * s);
            float4 wh0=wh4p[0], wh1=wh4p[1], wh2=wh4p[2], wh3=wh4p[3];
            float4 wh4=wh4p[4], wh5=wh4p[5], wh6=wh4p[6], wh7=wh4p[7];
            float bias = (s == 0) ? (b_ih2[g] + b_hh2[g]) : 0.f;

            float ain0 = bias; IN32(ain0, &h1c[0][0][32*s]);
            float ain1 = bias; IN32(ain1, &h1c[1][0][32*s]);

            #pragma unroll 1
            for (int tt = 0; tt < TC; ++tt) {
                float a0 = ain0; REC32(a0, &hst[2][0][32*s]);
                float a1 = ain1; REC32(a1, &hst[2][1][32*s]);
                float keep = s ? a1 : a0;
                float send = s ? a0 : a1;
                float v  = keep + __shfl_xor(send, 1, 64);
                float av = (gt == 2) ? tanhc(v) : sigm(v);
                gbuf[s][g] = av;
                __syncthreads();
                if (tid < TB * Hh) {
                    float iv = gbuf[cb][cu];
                    float fv = gbuf[cb][Hh + cu];
                    float gv = gbuf[cb][2*Hh + cu];
                    float ov = gbuf[cb][3*Hh + cu];
                    float c_ = fmaf(fv, c2s, iv * gv);
                    c2s = c_;
                    float hn = ov * tanhc(c_);
                    hst[2][cb][cu] = hn;   // only state needed for layer 2
                }
                if (tt + 1 < TC) {   // overlap next input-half with combine
                    ain0 = bias; IN32(ain0, &h1c[0][tt+1][32*s]);
                    ain1 = bias; IN32(ain1, &h1c[1][tt+1][32*s]);
                }
                __syncthreads();
            }
        }
    }

    // ---- final FC on h2 at t = T-1 ----
    if (tid < TB * Hh) {
        float p = hst[2][cb][cu] * w_fc[cu];
        #pragma unroll
        for (int off = 32; off > 0; off >>= 1) p += __shfl_down(p, off, 64);
        if (cu == 0) out[b0 + cb] = p + b_fc[0];
    }
}

extern "C" void kernel_launch(void* const* d_in, const int* in_sizes, int n_in,
                              void* d_out, int out_size, void* d_ws, size_t ws_size,
                              hipStream_t stream) {
    const float* x     = (const float*)d_in[0];
    const float* w_ih0 = (const float*)d_in[1];
    const float* w_hh0 = (const float*)d_in[2];
    const float* b_ih0 = (const float*)d_in[3];
    const float* b_hh0 = (const float*)d_in[4];
    const float* w_ih1 = (const float*)d_in[5];
    const float* w_hh1 = (const float*)d_in[6];
    const float* b_ih1 = (const float*)d_in[7];
    const float* b_hh1 = (const float*)d_in[8];
    const float* w_ih2 = (const float*)d_in[9];
    const float* w_hh2 = (const float*)d_in[10];
    const float* b_ih2 = (const float*)d_in[11];
    const float* b_hh2 = (const float*)d_in[12];
    const float* w_fc  = (const float*)d_in[13];
    const float* b_fc  = (const float*)d_in[14];
    float* out = (float*)d_out;

    lstm3_fused<<<NB, NT, 0, stream>>>(x,
        w_ih0, w_hh0, b_ih0, b_hh0,
        w_ih1, w_hh1, b_ih1, b_hh1,
        w_ih2, w_hh2, b_ih2, b_hh2,
        w_fc, b_fc, out, Tt / TC);
}

// Round 3
// 1565.198 us; speedup vs baseline: 1.9746x; 1.9746x over previous
//
#include <hip/hip_runtime.h>
#include <math.h>

// LSTM: I=5, H=64, L=3, O=1, B=1024, T=256, fp32.
// Round-6: r5 content with the launch-bounds regression reverted.
// r5 POST-MORTEM: __launch_bounds__(512,4) capped VGPR at 128 -> compiler
// spilled the 16 named weight float4s (64 VGPR of live-forever values) to
// scratch. Counters: FETCH_SIZE 3.9MB->3.9GB (reload every tt iter),
// WRITE_SIZE 16KB->310MB (spill once per layer), VALUBusy 63%->25% (vmcnt
// stalls). LDS=71680B caps occupancy at 2 blocks/CU anyway, so the tighter
// register bound bought nothing. DO NOT LOWER THE VGPR CAP ON THIS STRUCTURE
// (same failure as r1/r2's 21+ GB scratch).
// Kept from r5 (sound, previously masked by the spill):
//  (a) chained fmaf dot products (~48 ops/32 MACs -> 32)
//  (b) cheap activations via v_rcp/v_exp + dedup (lane s activates only batch
//      elem s) + single shfl_xor via operand cross-select
//  (c) software-pipelined input-half GEMM: ain(tt+1) reads only finalized
//      chunk buffers (xs/h0c/h1c), computed in the combine window so the
//      post-barrier critical path is REC32-only.
// Note: gbuf[s][g] all-lane write is a 2-way bank alias (addr g vs 256+g) ->
// SQ_LDS_BANK_CONFLICT ~1.2e8 but 2-way is ~free (m136); transposing gbuf
// would move the conflict to the 4-way read side. Leave as is.
// Structure: 512 blocks x 512 thr, TB=2 batch/block, k-split s=tid&1 (32
// weights/half), gate row g=tid>>1, weights in NAMED float4 registers,
// asm memory barriers to prevent weight-load hoisting.
// __launch_bounds__(512,2): 2 blocks/CU (LDS-limited), VGPR cap 256.

constexpr int Hh = 64;
constexpr int G4 = 256;   // 4*H gate rows
constexpr int Tt = 256;   // timesteps
constexpr int In = 5;     // input size
constexpr int TB = 2;     // batch elems per block
constexpr int TC = 64;    // timestep chunk
constexpr int NB = 512;   // blocks (NB*TB = 1024 = B)
constexpr int NT = 512;   // threads per block

// fast activations: v_mul + v_exp + v_add + v_rcp (+ v_fma for tanh)
__device__ __forceinline__ float sigm(float x) {
    return __builtin_amdgcn_rcpf(1.0f + exp2f(-1.442695041f * x));
}
__device__ __forceinline__ float tanhc(float x) {
    // tanh(x) = 2*sigmoid(2x) - 1; saturates correctly at +/-inf, NaN-free
    return fmaf(2.0f, __builtin_amdgcn_rcpf(1.0f + exp2f(-2.885390082f * x)), -1.0f);
}

#define FMA4(acc, W, H) do { \
    acc = fmaf((W).x, (H).x, acc); acc = fmaf((W).y, (H).y, acc); \
    acc = fmaf((W).z, (H).z, acc); acc = fmaf((W).w, (H).w, acc); } while (0)

// macros reference wh0..wh7 / wi0..wi7 named float4s from enclosing scope
#define REC32(acc, HPTR) do { \
    const float4* hp_ = reinterpret_cast<const float4*>(HPTR); \
    float4 hA=hp_[0], hB=hp_[1], hC=hp_[2], hD=hp_[3]; \
    float4 hE=hp_[4], hF=hp_[5], hG=hp_[6], hH=hp_[7]; \
    FMA4(acc,wh0,hA); FMA4(acc,wh1,hB); FMA4(acc,wh2,hC); FMA4(acc,wh3,hD); \
    FMA4(acc,wh4,hE); FMA4(acc,wh5,hF); FMA4(acc,wh6,hG); FMA4(acc,wh7,hH); \
} while (0)

#define IN32(acc, HPTR) do { \
    const float4* ip_ = reinterpret_cast<const float4*>(HPTR); \
    float4 iA=ip_[0], iB=ip_[1], iC=ip_[2], iD=ip_[3]; \
    float4 iE=ip_[4], iF=ip_[5], iG=ip_[6], iH=ip_[7]; \
    FMA4(acc,wi0,iA); FMA4(acc,wi1,iB); FMA4(acc,wi2,iC); FMA4(acc,wi3,iD); \
    FMA4(acc,wi4,iE); FMA4(acc,wi5,iF); FMA4(acc,wi6,iG); FMA4(acc,wi7,iH); \
} while (0)

__global__ __launch_bounds__(NT, 2) void lstm3_fused(
    const float* __restrict__ x,
    const float* __restrict__ w_ih0, const float* __restrict__ w_hh0,
    const float* __restrict__ b_ih0, const float* __restrict__ b_hh0,
    const float* __restrict__ w_ih1, const float* __restrict__ w_hh1,
    const float* __restrict__ b_ih1, const float* __restrict__ b_hh1,
    const float* __restrict__ w_ih2, const float* __restrict__ w_hh2,
    const float* __restrict__ b_ih2, const float* __restrict__ b_hh2,
    const float* __restrict__ w_fc,  const float* __restrict__ b_fc,
    float* __restrict__ out, int nch)
{
    __shared__ alignas(16) float h0c[TB][TC][Hh];   // layer0 output chunk (32 KB)
    __shared__ alignas(16) float h1c[TB][TC][Hh];   // layer1 output chunk (32 KB)
    __shared__ alignas(16) float hst[3][TB][Hh];    // recurrent h state per layer
    __shared__ alignas(16) float gbuf[TB][G4];      // activated gates
    __shared__ alignas(16) float xs[TB][TC][In];    // staged input chunk

    const int tid = threadIdx.x;
    const int g   = tid >> 1;         // gate row 0..255
    const int s   = tid & 1;          // k-half 0..1
    const int gt  = tid >> 7;         // 0:i 1:f 2:g~ 3:o (wave-uniform)
    const int b0  = blockIdx.x * TB;
    const int cu  = tid & (Hh - 1);   // combine: hidden unit (tid < 128)
    const int cb  = tid >> 6;         // combine: batch elem

    float c0s = 0.f, c1s = 0.f, c2s = 0.f;   // c state (threads tid < TB*Hh)

    for (int i = tid; i < 3 * TB * Hh; i += NT) ((float*)hst)[i] = 0.f;

    #pragma unroll 1
    for (int chunk = 0; chunk < nch; ++chunk) {
        const int t0 = chunk * TC;

        // ---- stage x chunk (tiny: 640 floats) ----
        for (int i = tid; i < TB * TC * In; i += NT) {
            int b  = i / (TC * In);
            int r  = i - b * (TC * In);
            int t  = r / In;
            int cc = r - t * In;
            xs[b][t][cc] = x[((size_t)(b0 + b) * Tt + (t0 + t)) * In + cc];
        }

        // ================= layer 0 =================
        {
            asm volatile("" ::: "memory");   // block hoist of weight loads
            float wiA0=0.f, wiA1=0.f, wiA2=0.f, wiA3=0.f, wiA4=0.f, bias=0.f;
            if (s == 0) {
                wiA0 = w_ih0[g*In+0]; wiA1 = w_ih0[g*In+1]; wiA2 = w_ih0[g*In+2];
                wiA3 = w_ih0[g*In+3]; wiA4 = w_ih0[g*In+4];
                bias = b_ih0[g] + b_hh0[g];
            }
            const float4* w4 = reinterpret_cast<const float4*>(w_hh0 + g * Hh + 32 * s);
            float4 wh0=w4[0], wh1=w4[1], wh2=w4[2], wh3=w4[3];
            float4 wh4=w4[4], wh5=w4[5], wh6=w4[6], wh7=w4[7];
            __syncthreads();   // xs staged (+ chunk 0: hst zero-init visible)

            // prefetch input-half for tt=0 (s==1 lanes compute 0: weights are 0)
            float ain0 = fmaf(wiA4, xs[0][0][4], fmaf(wiA3, xs[0][0][3],
                         fmaf(wiA2, xs[0][0][2], fmaf(wiA1, xs[0][0][1],
                         fmaf(wiA0, xs[0][0][0], bias)))));
            float ain1 = fmaf(wiA4, xs[1][0][4], fmaf(wiA3, xs[1][0][3],
                         fmaf(wiA2, xs[1][0][2], fmaf(wiA1, xs[1][0][1],
                         fmaf(wiA0, xs[1][0][0], bias)))));

            #pragma unroll 1
            for (int tt = 0; tt < TC; ++tt) {
                float a0 = ain0; REC32(a0, &hst[0][0][32*s]);
                float a1 = ain1; REC32(a1, &hst[0][1][32*s]);
                // single shuffle: keep own elem's partial, send partner's
                float keep = s ? a1 : a0;
                float send = s ? a0 : a1;
                float v  = keep + __shfl_xor(send, 1, 64);
                float av = (gt == 2) ? tanhc(v) : sigm(v);
                gbuf[s][g] = av;
                __syncthreads();
                if (tid < TB * Hh) {
                    float iv = gbuf[cb][cu];
                    float fv = gbuf[cb][Hh + cu];
                    float gv = gbuf[cb][2*Hh + cu];
                    float ov = gbuf[cb][3*Hh + cu];
                    float c_ = fmaf(fv, c0s, iv * gv);
                    c0s = c_;
                    float hn = ov * tanhc(c_);
                    hst[0][cb][cu] = hn;
                    h0c[cb][tt][cu] = hn;
                }
                if (tt + 1 < TC) {   // overlap next input-half with combine
                    ain0 = fmaf(wiA4, xs[0][tt+1][4], fmaf(wiA3, xs[0][tt+1][3],
                           fmaf(wiA2, xs[0][tt+1][2], fmaf(wiA1, xs[0][tt+1][1],
                           fmaf(wiA0, xs[0][tt+1][0], bias)))));
                    ain1 = fmaf(wiA4, xs[1][tt+1][4], fmaf(wiA3, xs[1][tt+1][3],
                           fmaf(wiA2, xs[1][tt+1][2], fmaf(wiA1, xs[1][tt+1][1],
                           fmaf(wiA0, xs[1][tt+1][0], bias)))));
                }
                __syncthreads();
            }
        }

        // ================= layer 1 =================
        {
            asm volatile("" ::: "memory");
            const float4* wi4p = reinterpret_cast<const float4*>(w_ih1 + g * Hh + 32 * s);
            float4 wi0=wi4p[0], wi1=wi4p[1], wi2=wi4p[2], wi3=wi4p[3];
            float4 wi4=wi4p[4], wi5=wi4p[5], wi6=wi4p[6], wi7=wi4p[7];
            const float4* wh4p = reinterpret_cast<const float4*>(w_hh1 + g * Hh + 32 * s);
            float4 wh0=wh4p[0], wh1=wh4p[1], wh2=wh4p[2], wh3=wh4p[3];
            float4 wh4=wh4p[4], wh5=wh4p[5], wh6=wh4p[6], wh7=wh4p[7];
            float bias = (s == 0) ? (b_ih1[g] + b_hh1[g]) : 0.f;
            // h0c fully written (final barrier of layer-0 loop)

            float ain0 = bias; IN32(ain0, &h0c[0][0][32*s]);
            float ain1 = bias; IN32(ain1, &h0c[1][0][32*s]);

            #pragma unroll 1
            for (int tt = 0; tt < TC; ++tt) {
                float a0 = ain0; REC32(a0, &hst[1][0][32*s]);
                float a1 = ain1; REC32(a1, &hst[1][1][32*s]);
                float keep = s ? a1 : a0;
                float send = s ? a0 : a1;
                float v  = keep + __shfl_xor(send, 1, 64);
                float av = (gt == 2) ? tanhc(v) : sigm(v);
                gbuf[s][g] = av;
                __syncthreads();
                if (tid < TB * Hh) {
                    float iv = gbuf[cb][cu];
                    float fv = gbuf[cb][Hh + cu];
                    float gv = gbuf[cb][2*Hh + cu];
                    float ov = gbuf[cb][3*Hh + cu];
                    float c_ = fmaf(fv, c1s, iv * gv);
                    c1s = c_;
                    float hn = ov * tanhc(c_);
                    hst[1][cb][cu] = hn;
                    h1c[cb][tt][cu] = hn;
                }
                if (tt + 1 < TC) {   // overlap next input-half with combine
                    ain0 = bias; IN32(ain0, &h0c[0][tt+1][32*s]);
                    ain1 = bias; IN32(ain1, &h0c[1][tt+1][32*s]);
                }
                __syncthreads();
            }
        }

        // ================= layer 2 =================
        {
            asm volatile("" ::: "memory");
            const float4* wi4p = reinterpret_cast<const float4*>(w_ih2 + g * Hh + 32 * s);
            float4 wi0=wi4p[0], wi1=wi4p[1], wi2=wi4p[2], wi3=wi4p[3];
            float4 wi4=wi4p[4], wi5=wi4p[5], wi6=wi4p[6], wi7=wi4p[7];
            const float4* wh4p = reinterpret_cast<const float4*>(w_hh2 + g * Hh + 32 * s);
            float4 wh0=wh4p[0], wh1=wh4p[1], wh2=wh4p[2], wh3=wh4p[3];
            float4 wh4=wh4p[4], wh5=wh4p[5], wh6=wh4p[6], wh7=wh4p[7];
            float bias = (s == 0) ? (b_ih2[g] + b_hh2[g]) : 0.f;

            float ain0 = bias; IN32(ain0, &h1c[0][0][32*s]);
            float ain1 = bias; IN32(ain1, &h1c[1][0][32*s]);

            #pragma unroll 1
            for (int tt = 0; tt < TC; ++tt) {
                float a0 = ain0; REC32(a0, &hst[2][0][32*s]);
                float a1 = ain1; REC32(a1, &hst[2][1][32*s]);
                float keep = s ? a1 : a0;
                float send = s ? a0 : a1;
                float v  = keep + __shfl_xor(send, 1, 64);
                float av = (gt == 2) ? tanhc(v) : sigm(v);
                gbuf[s][g] = av;
                __syncthreads();
                if (tid < TB * Hh) {
                    float iv = gbuf[cb][cu];
                    float fv = gbuf[cb][Hh + cu];
                    float gv = gbuf[cb][2*Hh + cu];
                    float ov = gbuf[cb][3*Hh + cu];
                    float c_ = fmaf(fv, c2s, iv * gv);
                    c2s = c_;
                    float hn = ov * tanhc(c_);
                    hst[2][cb][cu] = hn;   // only state needed for layer 2
                }
                if (tt + 1 < TC) {   // overlap next input-half with combine
                    ain0 = bias; IN32(ain0, &h1c[0][tt+1][32*s]);
                    ain1 = bias; IN32(ain1, &h1c[1][tt+1][32*s]);
                }
                __syncthreads();
            }
        }
    }

    // ---- final FC on h2 at t = T-1 ----
    if (tid < TB * Hh) {
        float p = hst[2][cb][cu] * w_fc[cu];
        #pragma unroll
        for (int off = 32; off > 0; off >>= 1) p += __shfl_down(p, off, 64);
        if (cu == 0) out[b0 + cb] = p + b_fc[0];
    }
}

extern "C" void kernel_launch(void* const* d_in, const int* in_sizes, int n_in,
                              void* d_out, int out_size, void* d_ws, size_t ws_size,
                              hipStream_t stream) {
    const float* x     = (const float*)d_in[0];
    const float* w_ih0 = (const float*)d_in[1];
    const float* w_hh0 = (const float*)d_in[2];
    const float* b_ih0 = (const float*)d_in[3];
    const float* b_hh0 = (const float*)d_in[4];
    const float* w_ih1 = (const float*)d_in[5];
    const float* w_hh1 = (const float*)d_in[6];
    const float* b_ih1 = (const float*)d_in[7];
    const float* b_hh1 = (const float*)d_in[8];
    const float* w_ih2 = (const float*)d_in[9];
    const float* w_hh2 = (const float*)d_in[10];
    const float* b_ih2 = (const float*)d_in[11];
    const float* b_hh2 = (const float*)d_in[12];
    const float* w_fc  = (const float*)d_in[13];
    const float* b_fc  = (const float*)d_in[14];
    float* out = (float*)d_out;

    lstm3_fused<<<NB, NT, 0, stream>>>(x,
        w_ih0, w_hh0, b_ih0, b_hh0,
        w_ih1, w_hh1, b_ih1, b_hh1,
        w_ih2, w_hh2, b_ih2, b_hh2,
        w_fc, b_fc, out, Tt / TC);
}

// Round 4
// 1553.007 us; speedup vs baseline: 1.9901x; 1.0078x over previous
//
#include <hip/hip_runtime.h>
#include <math.h>

// LSTM: I=5, H=64, L=3, O=1, B=1024, T=256, fp32.
// Round-7: single-barrier restructure.
// r6 POST-MORTEM: VALUBusy 63->48.6 but dur 1522->1565: NOT issue-bound;
// barrier/latency-bound (2 barriers/timestep + combine phase with 6/8 waves
// idle). This round: remap lanes so all 4 gates of a unit live in ONE wave:
//   lane l = gt(b0-1) | s(b2) | q(b3-5); unit u = (tid>>6)*8+q; row = gt*64+u
// - k-half reduce via shfl_xor(.,4) (keep/send trick as before)
// - gate gather via 3x shfl_xor(1/2) + 8 cndmask (branch-free)
// - EVERY lane computes c,h in-register (4x redundant over gt, identical)
// - hst double-buffered [layer][parity][b][u]: read p, write p^1 -> no race
// - ONE __syncthreads per timestep; gbuf + combine phase deleted
// Kept: named float4 weight regs (64 floats/thread - structural invariant:
// (w_hh+w_ih)/512 threads), chained fmaf dots, cheap rcp/exp activations
// (unified coeffs kExp/kA/kB hoisted, no divergence), ain software pipeline
// in the pre-barrier slot, asm anti-hoist barriers.
// VGPR: was 96; MUST stay <=128 (512 regs/SIMD / 4 waves) or occupancy
// halves to 1 block/CU. DO NOT add launch_bounds min-waves >2 (r5: cap 128
// made the allocator target 64 -> 4.3GB scratch spill).
// LDS: 65536(h0c,h1c) + 12288(hst x2 parity) + 2560(xs) = 80384 B -> 2/CU.

constexpr int Hh = 64;
constexpr int Tt = 256;   // timesteps
constexpr int In = 5;     // input size
constexpr int TB = 2;     // batch elems per block
constexpr int TC = 64;    // timestep chunk
constexpr int NB = 512;   // blocks (NB*TB = 1024 = B)
constexpr int NT = 512;   // threads per block

__device__ __forceinline__ float tanhc(float x) {
    // tanh(x) = 2*sigmoid(2x) - 1; saturates correctly at +/-inf, NaN-free
    return fmaf(2.0f, __builtin_amdgcn_rcpf(1.0f + exp2f(-2.885390082f * x)), -1.0f);
}

#define FMA4(acc, W, H) do { \
    acc = fmaf((W).x, (H).x, acc); acc = fmaf((W).y, (H).y, acc); \
    acc = fmaf((W).z, (H).z, acc); acc = fmaf((W).w, (H).w, acc); } while (0)

// macros reference wh0..wh7 / wi0..wi7 named float4s from enclosing scope
#define REC32(acc, HPTR) do { \
    const float4* hp_ = reinterpret_cast<const float4*>(HPTR); \
    float4 hA=hp_[0], hB=hp_[1], hC=hp_[2], hD=hp_[3]; \
    float4 hE=hp_[4], hF=hp_[5], hG=hp_[6], hH=hp_[7]; \
    FMA4(acc,wh0,hA); FMA4(acc,wh1,hB); FMA4(acc,wh2,hC); FMA4(acc,wh3,hD); \
    FMA4(acc,wh4,hE); FMA4(acc,wh5,hF); FMA4(acc,wh6,hG); FMA4(acc,wh7,hH); \
} while (0)

#define IN32(acc, HPTR) do { \
    const float4* ip_ = reinterpret_cast<const float4*>(HPTR); \
    float4 iA=ip_[0], iB=ip_[1], iC=ip_[2], iD=ip_[3]; \
    float4 iE=ip_[4], iF=ip_[5], iG=ip_[6], iH=ip_[7]; \
    FMA4(acc,wi0,iA); FMA4(acc,wi1,iB); FMA4(acc,wi2,iC); FMA4(acc,wi3,iD); \
    FMA4(acc,wi4,iE); FMA4(acc,wi5,iF); FMA4(acc,wi6,iG); FMA4(acc,wi7,iH); \
} while (0)

// gate-quad combine: reduce halves, activate, gather 4 gates, update c, h.
// Uses enclosing: s, gt, g1, g2, kExp, kA, kB. In: a0,a1 partials; c (ref).
// Out: hn.
#define GATE_COMBINE(a0, a1, cvar, hn) \
    float keep_ = s ? (a1) : (a0); \
    float send_ = s ? (a0) : (a1); \
    float v_  = keep_ + __shfl_xor(send_, 4, 64); \
    float e_  = exp2f(kExp * v_); \
    float av_ = fmaf(kA, __builtin_amdgcn_rcpf(1.0f + e_), kB); \
    float b1_ = __shfl_xor(av_, 1, 64);   /* gate gt^1 */ \
    float b2_ = __shfl_xor(av_, 2, 64);   /* gate gt^2 */ \
    float b3_ = __shfl_xor(b1_, 2, 64);   /* gate gt^3 */ \
    float x0_ = g1 ? b1_ : av_, x1_ = g1 ? av_ : b1_; \
    float y0_ = g1 ? b3_ : b2_, y1_ = g1 ? b2_ : b3_; \
    float iv_ = g2 ? y0_ : x0_, fv_ = g2 ? y1_ : x1_; \
    float gv_ = g2 ? x0_ : y0_, ov_ = g2 ? x1_ : y1_; \
    float c_  = fmaf(fv_, cvar, iv_ * gv_); \
    cvar = c_; \
    float hn = ov_ * tanhc(c_);

__global__ __launch_bounds__(NT, 2) void lstm3_fused(
    const float* __restrict__ x,
    const float* __restrict__ w_ih0, const float* __restrict__ w_hh0,
    const float* __restrict__ b_ih0, const float* __restrict__ b_hh0,
    const float* __restrict__ w_ih1, const float* __restrict__ w_hh1,
    const float* __restrict__ b_ih1, const float* __restrict__ b_hh1,
    const float* __restrict__ w_ih2, const float* __restrict__ w_hh2,
    const float* __restrict__ b_ih2, const float* __restrict__ b_hh2,
    const float* __restrict__ w_fc,  const float* __restrict__ b_fc,
    float* __restrict__ out, int nch)
{
    __shared__ alignas(16) float h0c[TB][TC][Hh];     // layer0 out chunk (32 KB)
    __shared__ alignas(16) float h1c[TB][TC][Hh];     // layer1 out chunk (32 KB)
    __shared__ alignas(16) float hst[3][2][TB][Hh];   // h state, double-buffered
    __shared__ alignas(16) float xs[TB][TC][In];      // staged input chunk

    const int tid = threadIdx.x;
    const int l   = tid & 63;          // lane
    const int gt  = l & 3;             // gate 0:i 1:f 2:g~ 3:o (intra-wave!)
    const int s   = (l >> 2) & 1;      // k-half AND owned batch elem
    const int u   = ((tid >> 6) << 3) | (l >> 3);   // hidden unit 0..63
    const int g   = (gt << 6) | u;     // gate row 0..255
    const bool g1 = (gt & 1) != 0;
    const bool g2 = (gt & 2) != 0;
    const int b0  = blockIdx.x * TB;
    const int cu  = tid & (Hh - 1);    // epilogue: hidden unit (tid < 128)
    const int cb  = tid >> 6;          // epilogue: batch elem

    // unified activation coefficients (gt==2 -> tanh, else sigmoid)
    const float kExp = (gt == 2) ? -2.885390082f : -1.442695041f;
    const float kA   = (gt == 2) ? 2.0f : 1.0f;
    const float kB   = (gt == 2) ? -1.0f : 0.0f;

    float c0s = 0.f, c1s = 0.f, c2s = 0.f;   // c state for (u, batch s)

    for (int i = tid; i < 3 * 2 * TB * Hh; i += NT) ((float*)hst)[i] = 0.f;

    #pragma unroll 1
    for (int chunk = 0; chunk < nch; ++chunk) {
        const int t0 = chunk * TC;

        // ---- stage x chunk (tiny: 640 floats) ----
        for (int i = tid; i < TB * TC * In; i += NT) {
            int b  = i / (TC * In);
            int r  = i - b * (TC * In);
            int t  = r / In;
            int cc = r - t * In;
            xs[b][t][cc] = x[((size_t)(b0 + b) * Tt + (t0 + t)) * In + cc];
        }

        // ================= layer 0 =================
        {
            asm volatile("" ::: "memory");   // block hoist of weight loads
            float wiA0=0.f, wiA1=0.f, wiA2=0.f, wiA3=0.f, wiA4=0.f, bias=0.f;
            if (s == 0) {
                wiA0 = w_ih0[g*In+0]; wiA1 = w_ih0[g*In+1]; wiA2 = w_ih0[g*In+2];
                wiA3 = w_ih0[g*In+3]; wiA4 = w_ih0[g*In+4];
                bias = b_ih0[g] + b_hh0[g];
            }
            const float4* w4 = reinterpret_cast<const float4*>(w_hh0 + g * Hh + 32 * s);
            float4 wh0=w4[0], wh1=w4[1], wh2=w4[2], wh3=w4[3];
            float4 wh4=w4[4], wh5=w4[5], wh6=w4[6], wh7=w4[7];
            __syncthreads();   // xs staged (+ chunk 0: hst zero-init visible)

            float ain0 = fmaf(wiA4, xs[0][0][4], fmaf(wiA3, xs[0][0][3],
                         fmaf(wiA2, xs[0][0][2], fmaf(wiA1, xs[0][0][1],
                         fmaf(wiA0, xs[0][0][0], bias)))));
            float ain1 = fmaf(wiA4, xs[1][0][4], fmaf(wiA3, xs[1][0][3],
                         fmaf(wiA2, xs[1][0][2], fmaf(wiA1, xs[1][0][1],
                         fmaf(wiA0, xs[1][0][0], bias)))));

            int p = 0;
            #pragma unroll 1
            for (int tt = 0; tt < TC; ++tt) {
                float a0 = ain0; REC32(a0, &hst[0][p][0][32*s]);
                float a1 = ain1; REC32(a1, &hst[0][p][1][32*s]);
                GATE_COMBINE(a0, a1, c0s, hn);
                if (gt == 0) {
                    hst[0][p^1][s][u] = hn;
                    h0c[s][tt][u]     = hn;
                }
                if (tt + 1 < TC) {   // overlap next input-half with barrier
                    ain0 = fmaf(wiA4, xs[0][tt+1][4], fmaf(wiA3, xs[0][tt+1][3],
                           fmaf(wiA2, xs[0][tt+1][2], fmaf(wiA1, xs[0][tt+1][1],
                           fmaf(wiA0, xs[0][tt+1][0], bias)))));
                    ain1 = fmaf(wiA4, xs[1][tt+1][4], fmaf(wiA3, xs[1][tt+1][3],
                           fmaf(wiA2, xs[1][tt+1][2], fmaf(wiA1, xs[1][tt+1][1],
                           fmaf(wiA0, xs[1][tt+1][0], bias)))));
                }
                __syncthreads();
                p ^= 1;
            }
        }

        // ================= layer 1 =================
        {
            asm volatile("" ::: "memory");
            const float4* wi4p = reinterpret_cast<const float4*>(w_ih1 + g * Hh + 32 * s);
            float4 wi0=wi4p[0], wi1=wi4p[1], wi2=wi4p[2], wi3=wi4p[3];
            float4 wi4=wi4p[4], wi5=wi4p[5], wi6=wi4p[6], wi7=wi4p[7];
            const float4* wh4p = reinterpret_cast<const float4*>(w_hh1 + g * Hh + 32 * s);
            float4 wh0=wh4p[0], wh1=wh4p[1], wh2=wh4p[2], wh3=wh4p[3];
            float4 wh4=wh4p[4], wh5=wh4p[5], wh6=wh4p[6], wh7=wh4p[7];
            float bias = (s == 0) ? (b_ih1[g] + b_hh1[g]) : 0.f;
            // h0c fully written (final barrier of layer-0 loop)

            float ain0 = bias; IN32(ain0, &h0c[0][0][32*s]);
            float ain1 = bias; IN32(ain1, &h0c[1][0][32*s]);

            int p = 0;
            #pragma unroll 1
            for (int tt = 0; tt < TC; ++tt) {
                float a0 = ain0; REC32(a0, &hst[1][p][0][32*s]);
                float a1 = ain1; REC32(a1, &hst[1][p][1][32*s]);
                GATE_COMBINE(a0, a1, c1s, hn);
                if (gt == 0) {
                    hst[1][p^1][s][u] = hn;
                    h1c[s][tt][u]     = hn;
                }
                if (tt + 1 < TC) {
                    ain0 = bias; IN32(ain0, &h0c[0][tt+1][32*s]);
                    ain1 = bias; IN32(ain1, &h0c[1][tt+1][32*s]);
                }
                __syncthreads();
                p ^= 1;
            }
        }

        // ================= layer 2 =================
        {
            asm volatile("" ::: "memory");
            const float4* wi4p = reinterpret_cast<const float4*>(w_ih2 + g * Hh + 32 * s);
            float4 wi0=wi4p[0], wi1=wi4p[1], wi2=wi4p[2], wi3=wi4p[3];
            float4 wi4=wi4p[4], wi5=wi4p[5], wi6=wi4p[6], wi7=wi4p[7];
            const float4* wh4p = reinterpret_cast<const float4*>(w_hh2 + g * Hh + 32 * s);
            float4 wh0=wh4p[0], wh1=wh4p[1], wh2=wh4p[2], wh3=wh4p[3];
            float4 wh4=wh4p[4], wh5=wh4p[5], wh6=wh4p[6], wh7=wh4p[7];
            float bias = (s == 0) ? (b_ih2[g] + b_hh2[g]) : 0.f;

            float ain0 = bias; IN32(ain0, &h1c[0][0][32*s]);
            float ain1 = bias; IN32(ain1, &h1c[1][0][32*s]);

            int p = 0;
            #pragma unroll 1
            for (int tt = 0; tt < TC; ++tt) {
                float a0 = ain0; REC32(a0, &hst[2][p][0][32*s]);
                float a1 = ain1; REC32(a1, &hst[2][p][1][32*s]);
                GATE_COMBINE(a0, a1, c2s, hn);
                if (gt == 0) {
                    hst[2][p^1][s][u] = hn;   // only state needed for layer 2
                }
                if (tt + 1 < TC) {
                    ain0 = bias; IN32(ain0, &h1c[0][tt+1][32*s]);
                    ain1 = bias; IN32(ain1, &h1c[1][tt+1][32*s]);
                }
                __syncthreads();
                p ^= 1;
            }
        }
    }

    // ---- final FC on h2 at t = T-1 (TC even -> final state at parity 0) ----
    if (tid < TB * Hh) {
        float p = hst[2][0][cb][cu] * w_fc[cu];
        #pragma unroll
        for (int off = 32; off > 0; off >>= 1) p += __shfl_down(p, off, 64);
        if (cu == 0) out[b0 + cb] = p + b_fc[0];
    }
}

extern "C" void kernel_launch(void* const* d_in, const int* in_sizes, int n_in,
                              void* d_out, int out_size, void* d_ws, size_t ws_size,
                              hipStream_t stream) {
    const float* x     = (const float*)d_in[0];
    const float* w_ih0 = (const float*)d_in[1];
    const float* w_hh0 = (const float*)d_in[2];
    const float* b_ih0 = (const float*)d_in[3];
    const float* b_hh0 = (const float*)d_in[4];
    const float* w_ih1 = (const float*)d_in[5];
    const float* w_hh1 = (const float*)d_in[6];
    const float* b_ih1 = (const float*)d_in[7];
    const float* b_hh1 = (const float*)d_in[8];
    const float* w_ih2 = (const float*)d_in[9];
    const float* w_hh2 = (const float*)d_in[10];
    const float* b_ih2 = (const float*)d_in[11];
    const float* b_hh2 = (const float*)d_in[12];
    const float* w_fc  = (const float*)d_in[13];
    const float* b_fc  = (const float*)d_in[14];
    float* out = (float*)d_out;

    lstm3_fused<<<NB, NT, 0, stream>>>(x,
        w_ih0, w_hh0, b_ih0, b_hh0,
        w_ih1, w_hh1, b_ih1, b_hh1,
        w_ih2, w_hh2, b_ih2, b_hh2,
        w_fc, b_fc, out, Tt / TC);
}

// Round 5
// 578.204 us; speedup vs baseline: 5.3453x; 2.6859x over previous
//
#include <hip/hip_runtime.h>
#include <math.h>

// LSTM: I=5, H=64, L=3, O=1, B=1024, T=256, fp32 in/out.
// Round-8: MFMA rewrite. r4-r7 showed the fp32-VALU structure is pinned at
// ~1520-1565 us across 3 different schedules: the CU-shared DS pipe (~512
// ds_read_b128/CU/iter) + serial chain latency is structural. This round
// moves the GEMMs to matrix cores:
//  - block = TB=16 batch elems, NT=768 (12 waves = 3 layer-groups x 4 waves)
//  - systolic layer pipeline: group g computes layer g at t = ti-g;
//    258 iterations, ONE barrier per iteration
//  - gates[16x256] = h[16x64] @ W^T via mfma_f32_16x16x32_bf16
//  - weights bf16 (RNE) in registers, loaded once pre-loop (8 frags whh +
//    8 frags wih per wave = 64 VGPR); h carried as bf16 hi+lo pair
//    (split-precision: 2 MFMA products; dynamic-path error ~2^-16)
//  - wave w owns units [16w,16w+16): its 4 C-tiles are i,f,g,o for the SAME
//    (b,u) in the same lane -> gate combine + c-state fully in-register
//  - h exchanged via small double-buffered LDS (stride 72 pad -> 2-way max)
// C/D layout (m89-verified): col=lane&15, row=(lane>>4)*4+reg.
// A layout assumed: row=lane&15, k=(lane>>4)*8+j; B: col=lane&15, same k.
// __launch_bounds__(768,3): 3 waves/EU -> VGPR cap 170 (est. use ~140).
// If FETCH_SIZE explodes -> spill -> revert pipeline depth next round.

typedef __attribute__((ext_vector_type(8))) short bf16x8;
typedef __attribute__((ext_vector_type(4))) float f32x4;

constexpr int Hh = 64;
constexpr int Tt = 256;
constexpr int In = 5;
constexpr int TB = 16;    // batch elems per block
constexpr int NB = 64;    // blocks (NB*TB = 1024 = B)
constexpr int NT = 768;   // threads (12 waves)
constexpr int HS = 72;    // padded h stride in elements (bank-spread)

__device__ __forceinline__ float sigm(float x) {
    return __builtin_amdgcn_rcpf(1.0f + exp2f(-1.442695041f * x));
}
__device__ __forceinline__ float tanhc(float x) {
    return fmaf(2.0f, __builtin_amdgcn_rcpf(1.0f + exp2f(-2.885390082f * x)), -1.0f);
}

// fp32 -> bf16 round-to-nearest-even (weights; finite values only)
__device__ __forceinline__ short f2bf_rne(float f) {
    union { float f; unsigned u; } v; v.f = f;
    unsigned r = (v.u + 0x7fffu + ((v.u >> 16) & 1u)) >> 16;
    return (short)r;
}
// fp32 -> (hi,lo) bf16 pair via truncation; hi+lo ~= f to ~2^-16 rel
__device__ __forceinline__ void split_bf(float f, short& hi, short& lo) {
    union { float f; unsigned u; } v; v.f = f;
    hi = (short)(v.u >> 16);
    union { unsigned u; float f; } h; h.u = v.u & 0xffff0000u;
    float r = f - h.f;
    union { float f; unsigned u; } w; w.f = r;
    lo = (short)(w.u >> 16);
}

// Build a B-fragment: 8 consecutive k of row n from row-major W[.][stride].
// Lane's elements: k = k0 + j (zero-padded past kmax).
__device__ __forceinline__ bf16x8 ldwfrag(const float* __restrict__ W,
                                          int n, int stride, int k0, int kmax) {
    bf16x8 r;
    #pragma unroll
    for (int j = 0; j < 8; ++j) {
        int k = k0 + j;
        float f = (k < kmax) ? W[n * stride + k] : 0.0f;
        r[j] = f2bf_rne(f);
    }
    return r;
}

__global__ __launch_bounds__(NT, 3) void lstm3_mfma(
    const float* __restrict__ x,
    const float* __restrict__ w_ih0, const float* __restrict__ w_hh0,
    const float* __restrict__ b_ih0, const float* __restrict__ b_hh0,
    const float* __restrict__ w_ih1, const float* __restrict__ w_hh1,
    const float* __restrict__ b_ih1, const float* __restrict__ b_hh1,
    const float* __restrict__ w_ih2, const float* __restrict__ w_hh2,
    const float* __restrict__ b_ih2, const float* __restrict__ b_hh2,
    const float* __restrict__ w_fc,  const float* __restrict__ b_fc,
    float* __restrict__ out)
{
    // h state per layer, double-buffered by iteration parity, bf16 hi/lo.
    __shared__ short hbhi[3][2][TB][HS];
    __shared__ short hblo[3][2][TB][HS];

    const int tid = threadIdx.x;
    const int l   = tid & 63;
    const int wid = tid >> 6;        // 0..11
    const int wg  = wid >> 2;        // layer group 0..2
    const int w4  = wid & 3;         // wave within layer
    const int ub  = w4 * 16;         // unit base (N-range [ub,ub+16))
    const int col = l & 15;          // A-row (batch) / B-col (unit) index
    const int kg  = l >> 4;          // k-group 0..3
    const int b0  = blockIdx.x * TB;

    // ---- zero LDS (covers pipeline-fill "h(t<0)=0" reads) ----
    {
        int* p = (int*)hbhi;
        for (int i = tid; i < 3 * 2 * TB * HS / 2; i += NT) p[i] = 0;
        int* q = (int*)hblo;
        for (int i = tid; i < 3 * 2 * TB * HS / 2; i += NT) q[i] = 0;
    }

    // ---- per-layer weight selection ----
    const float* whh = (wg == 0) ? w_hh0 : (wg == 1) ? w_hh1 : w_hh2;
    const float* wih = (wg == 0) ? w_ih0 : (wg == 1) ? w_ih1 : w_ih2;
    const float* bih = (wg == 0) ? b_ih0 : (wg == 1) ? b_ih1 : b_ih2;
    const float* bhh = (wg == 0) ? b_hh0 : (wg == 1) ? b_hh1 : b_hh2;

    // ---- weights -> register fragments (once) ----
    // B-frag for tile (gate gi, ktile kt): B[k][n] = W[n][k],
    // lane: n = gi*64 + ub + col, k = kt*32 + kg*8 + j.
    bf16x8 WH[4][2], WI[4][2];
    float  bs[4];
    #pragma unroll
    for (int gi = 0; gi < 4; ++gi) {
        int n = gi * 64 + ub + col;
        bs[gi] = bih[n] + bhh[n];
        #pragma unroll
        for (int kt = 0; kt < 2; ++kt) {
            WH[gi][kt] = ldwfrag(whh, n, Hh, kt * 32 + kg * 8, Hh);
            if (wg == 0) {
                // layer-0 input K=5 (single ktile, zero-padded)
                WI[gi][kt] = (kt == 0) ? ldwfrag(wih, n, In, kg * 8, In)
                                       : ldwfrag(wih, n, In, 64, 0); // zeros
            } else {
                WI[gi][kt] = ldwfrag(wih, n, Hh, kt * 32 + kg * 8, Hh);
            }
        }
    }

    // ---- x prefetch (layer-0 waves; lane holds x[b=col][t][0..4]) ----
    float xr[5] = {0.f, 0.f, 0.f, 0.f, 0.f};
    if (wg == 0 && kg == 0) {
        #pragma unroll
        for (int j = 0; j < In; ++j)
            xr[j] = x[((size_t)(b0 + col) * Tt + 0) * In + j];
    }

    float c[4] = {0.f, 0.f, 0.f, 0.f};   // cell state for (b=kg*4+j, u=ub+col)

    __syncthreads();

    // ---- systolic main loop: 258 iterations, 1 barrier each ----
    #pragma unroll 1
    for (int ti = 0; ti < Tt + 2; ++ti) {
        const int wp = ti & 1, rp = wp ^ 1;
        const bool act = (wg == 0) ? (ti < Tt)
                       : (wg == 1) ? (ti >= 1 && ti <= Tt)
                                   : (ti >= 2);
        if (act) {
            f32x4 acc[4];
            #pragma unroll
            for (int gi = 0; gi < 4; ++gi)
                acc[gi] = (f32x4){bs[gi], bs[gi], bs[gi], bs[gi]};

            // -------- recurrent GEMM: h_own(t-1) --------
            #pragma unroll
            for (int kt = 0; kt < 2; ++kt) {
                bf16x8 ahi = *(const bf16x8*)&hbhi[wg][rp][col][kt * 32 + kg * 8];
                bf16x8 alo = *(const bf16x8*)&hblo[wg][rp][col][kt * 32 + kg * 8];
                #pragma unroll
                for (int gi = 0; gi < 4; ++gi) {
                    acc[gi] = __builtin_amdgcn_mfma_f32_16x16x32_bf16(ahi, WH[gi][kt], acc[gi], 0, 0, 0);
                    acc[gi] = __builtin_amdgcn_mfma_f32_16x16x32_bf16(alo, WH[gi][kt], acc[gi], 0, 0, 0);
                }
            }

            // -------- input GEMM --------
            if (wg == 0) {
                // x(t=ti): build A-frag in-register (rows=col, k=kg*8+j, k<5)
                bf16x8 xhi, xlo;
                #pragma unroll
                for (int j = 0; j < 8; ++j) { xhi[j] = 0; xlo[j] = 0; }
                if (kg == 0) {
                    #pragma unroll
                    for (int j = 0; j < In; ++j) {
                        short h_, l_; split_bf(xr[j], h_, l_);
                        xhi[j] = h_; xlo[j] = l_;
                    }
                }
                #pragma unroll
                for (int gi = 0; gi < 4; ++gi) {
                    acc[gi] = __builtin_amdgcn_mfma_f32_16x16x32_bf16(xhi, WI[gi][0], acc[gi], 0, 0, 0);
                    acc[gi] = __builtin_amdgcn_mfma_f32_16x16x32_bf16(xlo, WI[gi][0], acc[gi], 0, 0, 0);
                }
                if (kg == 0 && ti + 1 < Tt) {   // prefetch next t
                    #pragma unroll
                    for (int j = 0; j < In; ++j)
                        xr[j] = x[((size_t)(b0 + col) * Tt + (ti + 1)) * In + j];
                }
            } else {
                const int lw = wg - 1;   // input = lower layer's h(t), parity rp
                #pragma unroll
                for (int kt = 0; kt < 2; ++kt) {
                    bf16x8 ahi = *(const bf16x8*)&hbhi[lw][rp][col][kt * 32 + kg * 8];
                    bf16x8 alo = *(const bf16x8*)&hblo[lw][rp][col][kt * 32 + kg * 8];
                    #pragma unroll
                    for (int gi = 0; gi < 4; ++gi) {
                        acc[gi] = __builtin_amdgcn_mfma_f32_16x16x32_bf16(ahi, WI[gi][kt], acc[gi], 0, 0, 0);
                        acc[gi] = __builtin_amdgcn_mfma_f32_16x16x32_bf16(alo, WI[gi][kt], acc[gi], 0, 0, 0);
                    }
                }
            }

            // -------- gate combine (in-register) + h publish --------
            // C rows: b = kg*4 + j; col: u = ub + col. acc[0..3] = i,f,g~,o.
            #pragma unroll
            for (int j = 0; j < 4; ++j) {
                float iv = sigm(acc[0][j]);
                float fv = sigm(acc[1][j]);
                float gv = tanhc(acc[2][j]);
                float ov = sigm(acc[3][j]);
                float cn = fmaf(fv, c[j], iv * gv);
                c[j] = cn;
                float hn = ov * tanhc(cn);
                short hhi_, hlo_; split_bf(hn, hhi_, hlo_);
                int b = kg * 4 + j;
                hbhi[wg][wp][b][ub + col] = hhi_;
                hblo[wg][wp][b][ub + col] = hlo_;
            }
        }
        __syncthreads();
    }

    // ---- final FC on h2(T-1): written at ti=Tt+1 -> parity (Tt+1)&1 ----
    if (tid < TB) {
        const int fp = (Tt + 1) & 1;
        const int b  = tid;
        float accf = b_fc[0];
        #pragma unroll 1
        for (int u = 0; u < Hh; ++u) {
            unsigned hu = ((unsigned)(unsigned short)hbhi[2][fp][b][u]) << 16;
            unsigned lu = ((unsigned)(unsigned short)hblo[2][fp][b][u]) << 16;
            union { unsigned u; float f; } A, L; A.u = hu; L.u = lu;
            accf = fmaf(A.f + L.f, w_fc[u], accf);
        }
        out[b0 + b] = accf;
    }
}

extern "C" void kernel_launch(void* const* d_in, const int* in_sizes, int n_in,
                              void* d_out, int out_size, void* d_ws, size_t ws_size,
                              hipStream_t stream) {
    const float* x     = (const float*)d_in[0];
    const float* w_ih0 = (const float*)d_in[1];
    const float* w_hh0 = (const float*)d_in[2];
    const float* b_ih0 = (const float*)d_in[3];
    const float* b_hh0 = (const float*)d_in[4];
    const float* w_ih1 = (const float*)d_in[5];
    const float* w_hh1 = (const float*)d_in[6];
    const float* b_ih1 = (const float*)d_in[7];
    const float* b_hh1 = (const float*)d_in[8];
    const float* w_ih2 = (const float*)d_in[9];
    const float* w_hh2 = (const float*)d_in[10];
    const float* b_ih2 = (const float*)d_in[11];
    const float* b_hh2 = (const float*)d_in[12];
    const float* w_fc  = (const float*)d_in[13];
    const float* b_fc  = (const float*)d_in[14];
    float* out = (float*)d_out;

    lstm3_mfma<<<NB, NT, 0, stream>>>(x,
        w_ih0, w_hh0, b_ih0, b_hh0,
        w_ih1, w_hh1, b_ih1, b_hh1,
        w_ih2, w_hh2, b_ih2, b_hh2,
        w_fc, b_fc, out);
}

// Round 6
// 571.580 us; speedup vs baseline: 5.4072x; 1.0116x over previous
//
#include <hip/hip_runtime.h>
#include <math.h>

// LSTM: I=5, H=64, L=3, O=1, B=1024, T=256, fp32 in/out.
// Round-9: spread the issue load across the whole chip.
// r8 POST-MORTEM (510us): counters are chip-averaged; with only 64 blocks
// (=64 active CUs of 256) the ACTIVE-CU numbers were VALUBusy ~72%,
// MfmaUtil ~30%, Occ ~36% -> issue-bound on 1/4 of the chip.
// This round: TB=4 real batch rows per block, NB=256 blocks -> 1 block/CU
// on all 256 CUs. MFMA M-tile stays 16 (rows 4..15 multiply zeros - MFMA
// has headroom); gate-combine guarded kg==0 so 3/4 of lanes skip the
// transcendental section entirely; h rows >= TB stay zero in LDS (never
// written) so A-frags are clean; x batch index clamped (col 4..15 would
// be OOB). Everything else = r8 structure:
//  - 12 waves = 3 layer-groups x 4 waves; systolic layer pipeline,
//    258 iters, ONE barrier per iter
//  - weights bf16 RNE in registers (16 frags/wave); h as bf16 hi+lo pair
//  - wave w owns units [16w,16w+16): 4 C-tiles = i,f,g,o same (b,u) lane
//    -> gate combine + c-state fully in-register
//  - h via double-buffered LDS, stride 72 (2-way max)
// C/D layout (m89): col=lane&15, row=(lane>>4)*4+reg. A: row=lane&15,
// k=(lane>>4)*8+j (hw-verified by r8's absmax=2.4e-4 pass).
// VGPR=68 -> 16 waves/CU cap -> exactly one 12-wave block per CU.
// DO NOT raise launch_bounds min-waves (r5: VGPR cap -> 4.3GB scratch).

typedef __attribute__((ext_vector_type(8))) short bf16x8;
typedef __attribute__((ext_vector_type(4))) float f32x4;

constexpr int Hh = 64;
constexpr int Tt = 256;
constexpr int In = 5;
constexpr int TBr = 4;    // REAL batch elems per block
constexpr int TBt = 16;   // MFMA M-tile (rows TBr..15 are zero)
constexpr int NB = 256;   // blocks (NB*TBr = 1024 = B)
constexpr int NT = 768;   // threads (12 waves)
constexpr int HS = 72;    // padded h stride in elements (bank-spread)

__device__ __forceinline__ float sigm(float x) {
    return __builtin_amdgcn_rcpf(1.0f + exp2f(-1.442695041f * x));
}
__device__ __forceinline__ float tanhc(float x) {
    return fmaf(2.0f, __builtin_amdgcn_rcpf(1.0f + exp2f(-2.885390082f * x)), -1.0f);
}

// fp32 -> bf16 round-to-nearest-even (weights; finite values only)
__device__ __forceinline__ short f2bf_rne(float f) {
    union { float f; unsigned u; } v; v.f = f;
    unsigned r = (v.u + 0x7fffu + ((v.u >> 16) & 1u)) >> 16;
    return (short)r;
}
// fp32 -> (hi,lo) bf16 pair via truncation; hi+lo ~= f to ~2^-16 rel
__device__ __forceinline__ void split_bf(float f, short& hi, short& lo) {
    union { float f; unsigned u; } v; v.f = f;
    hi = (short)(v.u >> 16);
    union { unsigned u; float f; } h; h.u = v.u & 0xffff0000u;
    float r = f - h.f;
    union { float f; unsigned u; } w; w.f = r;
    lo = (short)(w.u >> 16);
}

// Build a B-fragment: 8 consecutive k of row n from row-major W[.][stride].
__device__ __forceinline__ bf16x8 ldwfrag(const float* __restrict__ W,
                                          int n, int stride, int k0, int kmax) {
    bf16x8 r;
    #pragma unroll
    for (int j = 0; j < 8; ++j) {
        int k = k0 + j;
        float f = (k < kmax) ? W[n * stride + k] : 0.0f;
        r[j] = f2bf_rne(f);
    }
    return r;
}

__global__ __launch_bounds__(NT, 2) void lstm3_mfma(
    const float* __restrict__ x,
    const float* __restrict__ w_ih0, const float* __restrict__ w_hh0,
    const float* __restrict__ b_ih0, const float* __restrict__ b_hh0,
    const float* __restrict__ w_ih1, const float* __restrict__ w_hh1,
    const float* __restrict__ b_ih1, const float* __restrict__ b_hh1,
    const float* __restrict__ w_ih2, const float* __restrict__ w_hh2,
    const float* __restrict__ b_ih2, const float* __restrict__ b_hh2,
    const float* __restrict__ w_fc,  const float* __restrict__ b_fc,
    float* __restrict__ out)
{
    // h state per layer, double-buffered by iteration parity, bf16 hi/lo.
    // Rows TBr..15 stay zero forever (zero-filled, never written).
    __shared__ short hbhi[3][2][TBt][HS];
    __shared__ short hblo[3][2][TBt][HS];

    const int tid = threadIdx.x;
    const int l   = tid & 63;
    const int wid = tid >> 6;        // 0..11
    const int wg  = wid >> 2;        // layer group 0..2
    const int w4  = wid & 3;         // wave within layer
    const int ub  = w4 * 16;         // unit base (N-range [ub,ub+16))
    const int col = l & 15;          // A-row (batch) / B-col (unit) index
    const int kg  = l >> 4;          // k-group 0..3
    const int b0  = blockIdx.x * TBr;

    // ---- zero LDS (covers pipeline-fill and dead rows) ----
    {
        int* p = (int*)hbhi;
        for (int i = tid; i < 3 * 2 * TBt * HS / 2; i += NT) p[i] = 0;
        int* q = (int*)hblo;
        for (int i = tid; i < 3 * 2 * TBt * HS / 2; i += NT) q[i] = 0;
    }

    // ---- per-layer weight selection ----
    const float* whh = (wg == 0) ? w_hh0 : (wg == 1) ? w_hh1 : w_hh2;
    const float* wih = (wg == 0) ? w_ih0 : (wg == 1) ? w_ih1 : w_ih2;
    const float* bih = (wg == 0) ? b_ih0 : (wg == 1) ? b_ih1 : b_ih2;
    const float* bhh = (wg == 0) ? b_hh0 : (wg == 1) ? b_hh1 : b_hh2;

    // ---- weights -> register fragments (once) ----
    bf16x8 WH[4][2], WI[4][2];
    float  bs[4];
    #pragma unroll
    for (int gi = 0; gi < 4; ++gi) {
        int n = gi * 64 + ub + col;
        bs[gi] = bih[n] + bhh[n];
        #pragma unroll
        for (int kt = 0; kt < 2; ++kt) {
            WH[gi][kt] = ldwfrag(whh, n, Hh, kt * 32 + kg * 8, Hh);
            if (wg == 0) {
                WI[gi][kt] = (kt == 0) ? ldwfrag(wih, n, In, kg * 8, In)
                                       : ldwfrag(wih, n, In, 64, 0); // zeros
            } else {
                WI[gi][kt] = ldwfrag(wih, n, Hh, kt * 32 + kg * 8, Hh);
            }
        }
    }

    // ---- x prefetch (layer-0 waves; lane holds x[b=colc][t][0..4]) ----
    const int colc = (col < TBr) ? col : (TBr - 1);   // clamp (cols>=TBr unused)
    float xr[5] = {0.f, 0.f, 0.f, 0.f, 0.f};
    if (wg == 0 && kg == 0) {
        #pragma unroll
        for (int j = 0; j < In; ++j)
            xr[j] = x[((size_t)(b0 + colc) * Tt + 0) * In + j];
    }

    float c[4] = {0.f, 0.f, 0.f, 0.f};   // cell state (rows kg*4+j; kg==0 real)

    __syncthreads();

    // ---- systolic main loop: 258 iterations, 1 barrier each ----
    #pragma unroll 1
    for (int ti = 0; ti < Tt + 2; ++ti) {
        const int wp = ti & 1, rp = wp ^ 1;
        const bool act = (wg == 0) ? (ti < Tt)
                       : (wg == 1) ? (ti >= 1 && ti <= Tt)
                                   : (ti >= 2);
        if (act) {
            f32x4 acc[4];
            #pragma unroll
            for (int gi = 0; gi < 4; ++gi)
                acc[gi] = (f32x4){bs[gi], bs[gi], bs[gi], bs[gi]};

            // -------- recurrent GEMM: h_own(t-1) --------
            #pragma unroll
            for (int kt = 0; kt < 2; ++kt) {
                bf16x8 ahi = *(const bf16x8*)&hbhi[wg][rp][col][kt * 32 + kg * 8];
                bf16x8 alo = *(const bf16x8*)&hblo[wg][rp][col][kt * 32 + kg * 8];
                #pragma unroll
                for (int gi = 0; gi < 4; ++gi) {
                    acc[gi] = __builtin_amdgcn_mfma_f32_16x16x32_bf16(ahi, WH[gi][kt], acc[gi], 0, 0, 0);
                    acc[gi] = __builtin_amdgcn_mfma_f32_16x16x32_bf16(alo, WH[gi][kt], acc[gi], 0, 0, 0);
                }
            }

            // -------- input GEMM --------
            if (wg == 0) {
                bf16x8 xhi, xlo;
                #pragma unroll
                for (int j = 0; j < 8; ++j) { xhi[j] = 0; xlo[j] = 0; }
                if (kg == 0) {
                    #pragma unroll
                    for (int j = 0; j < In; ++j) {
                        short h_, l_; split_bf(xr[j], h_, l_);
                        xhi[j] = h_; xlo[j] = l_;
                    }
                }
                #pragma unroll
                for (int gi = 0; gi < 4; ++gi) {
                    acc[gi] = __builtin_amdgcn_mfma_f32_16x16x32_bf16(xhi, WI[gi][0], acc[gi], 0, 0, 0);
                    acc[gi] = __builtin_amdgcn_mfma_f32_16x16x32_bf16(xlo, WI[gi][0], acc[gi], 0, 0, 0);
                }
                if (kg == 0 && ti + 1 < Tt) {   // prefetch next t
                    #pragma unroll
                    for (int j = 0; j < In; ++j)
                        xr[j] = x[((size_t)(b0 + colc) * Tt + (ti + 1)) * In + j];
                }
            } else {
                const int lw = wg - 1;   // input = lower layer's h(t), parity rp
                #pragma unroll
                for (int kt = 0; kt < 2; ++kt) {
                    bf16x8 ahi = *(const bf16x8*)&hbhi[lw][rp][col][kt * 32 + kg * 8];
                    bf16x8 alo = *(const bf16x8*)&hblo[lw][rp][col][kt * 32 + kg * 8];
                    #pragma unroll
                    for (int gi = 0; gi < 4; ++gi) {
                        acc[gi] = __builtin_amdgcn_mfma_f32_16x16x32_bf16(ahi, WI[gi][kt], acc[gi], 0, 0, 0);
                        acc[gi] = __builtin_amdgcn_mfma_f32_16x16x32_bf16(alo, WI[gi][kt], acc[gi], 0, 0, 0);
                    }
                }
            }

            // -------- gate combine + h publish: ONLY real rows (kg==0) ----
            // C rows: b = kg*4 + j -> kg==0 covers b=0..3 = all real rows.
            if (kg == 0) {
                #pragma unroll
                for (int j = 0; j < 4; ++j) {
                    float iv = sigm(acc[0][j]);
                    float fv = sigm(acc[1][j]);
                    float gv = tanhc(acc[2][j]);
                    float ov = sigm(acc[3][j]);
                    float cn = fmaf(fv, c[j], iv * gv);
                    c[j] = cn;
                    float hn = ov * tanhc(cn);
                    short hhi_, hlo_; split_bf(hn, hhi_, hlo_);
                    hbhi[wg][wp][j][ub + col] = hhi_;
                    hblo[wg][wp][j][ub + col] = hlo_;
                }
            }
        }
        __syncthreads();
    }

    // ---- final FC on h2(T-1): written at ti=Tt+1 -> parity (Tt+1)&1 ----
    if (tid < TBr) {
        const int fp = (Tt + 1) & 1;
        const int b  = tid;
        float accf = b_fc[0];
        #pragma unroll 1
        for (int u = 0; u < Hh; ++u) {
            unsigned hu = ((unsigned)(unsigned short)hbhi[2][fp][b][u]) << 16;
            unsigned lu = ((unsigned)(unsigned short)hblo[2][fp][b][u]) << 16;
            union { unsigned u; float f; } A, L; A.u = hu; L.u = lu;
            accf = fmaf(A.f + L.f, w_fc[u], accf);
        }
        out[b0 + b] = accf;
    }
}

extern "C" void kernel_launch(void* const* d_in, const int* in_sizes, int n_in,
                              void* d_out, int out_size, void* d_ws, size_t ws_size,
                              hipStream_t stream) {
    const float* x     = (const float*)d_in[0];
    const float* w_ih0 = (const float*)d_in[1];
    const float* w_hh0 = (const float*)d_in[2];
    const float* b_ih0 = (const float*)d_in[3];
    const float* b_hh0 = (const float*)d_in[4];
    const float* w_ih1 = (const float*)d_in[5];
    const float* w_hh1 = (const float*)d_in[6];
    const float* b_ih1 = (const float*)d_in[7];
    const float* b_hh1 = (const float*)d_in[8];
    const float* w_ih2 = (const float*)d_in[9];
    const float* w_hh2 = (const float*)d_in[10];
    const float* b_ih2 = (const float*)d_in[11];
    const float* b_hh2 = (const float*)d_in[12];
    const float* w_fc  = (const float*)d_in[13];
    const float* b_fc  = (const float*)d_in[14];
    float* out = (float*)d_out;

    lstm3_mfma<<<NB, NT, 0, stream>>>(x,
        w_ih0, w_hh0, b_ih0, b_hh0,
        w_ih1, w_hh1, b_ih1, b_hh1,
        w_ih2, w_hh2, b_ih2, b_hh2,
        w_fc, b_fc, out);
}

// Round 8
// 557.650 us; speedup vs baseline: 5.5423x; 1.0250x over previous
//
#include <hip/hip_runtime.h>
#include <math.h>

// LSTM: I=5, H=64, L=3, O=1, B=1024, T=256, fp32 in/out.
// Round-11: r10 with the read-base addressing bug fixed.
// r10 POST-MORTEM (absmax 1.56e-2 FAIL): fused-LDS read base pointers
// dropped the k-group term. r8 read A-frags at [col][kt*32 + kg*8]; r10's
// rbB_/roA/roB had col*RB_ but no kg*16 bytes -> every k-group read k-slice
// [0,8) of each ktile. FIX: + kg*16 folded into the (lane-constant,
// loop-invariant) read bases. Write side + FC epilogue were correct.
// Kept from r10:
//  1) ONE fused LDS array [parity 16384B | layer 4608 | hi/lo 2304 | row
//     144]: ds ops are imm offsets from loop-invariant base pointers;
//     parity via manual 2x unroll (A/B pointer sets).
//  2) persistent xhi/xlo frags (zero-init once; kg==0 lanes overwrite 0..4).
//  3) s_setprio(1) around MFMA cluster.
// Structure (r8): TBt=16 batch/block, NB=64, 12 waves = 3 layer-groups x 4;
// systolic pipeline (group g does layer g at t=ti-g), 258 iters, 1
// barrier/iter; weights bf16 RNE in regs; h as bf16 hi+lo pair; wave w4
// owns units [16*w4,16*w4+16): C-tiles = i,f,g~,o same (b,u) lane.
// C/D layout (m89): col=lane&15, row=(lane>>4)*4+reg. A: row=lane&15,
// k=(lane>>4)*8+j (r8 hw-verified, absmax 2.4e-4).
// DO NOT raise launch_bounds min-waves (r5: VGPR cap -> 4.3GB scratch).

typedef __attribute__((ext_vector_type(8))) short bf16x8;
typedef __attribute__((ext_vector_type(4))) float f32x4;

constexpr int Hh  = 64;
constexpr int Tt  = 256;
constexpr int In  = 5;
constexpr int TBt = 16;    // batch rows per block (all real)
constexpr int NB  = 64;    // blocks (NB*TBt = 1024 = B)
constexpr int NT  = 768;   // threads (12 waves)

// LDS geometry (bytes): one array, immediate-offset addressable.
constexpr int RB_ = 144;    // row stride (72 shorts, bank-spread pad)
constexpr int HLB = 2304;   // hi -> lo offset (16 rows * 144)
constexpr int LB  = 4608;   // layer stride (2 * 2304)
constexpr int PB  = 16384;  // parity stride (13824 used, padded to pow2)

__device__ __forceinline__ float sigm(float x) {
    return __builtin_amdgcn_rcpf(1.0f + exp2f(-1.442695041f * x));
}
__device__ __forceinline__ float tanhc(float x) {
    return fmaf(2.0f, __builtin_amdgcn_rcpf(1.0f + exp2f(-2.885390082f * x)), -1.0f);
}

// fp32 -> bf16 round-to-nearest-even (weights; finite values only)
__device__ __forceinline__ short f2bf_rne(float f) {
    union { float f; unsigned u; } v; v.f = f;
    unsigned r = (v.u + 0x7fffu + ((v.u >> 16) & 1u)) >> 16;
    return (short)r;
}
// fp32 -> (hi,lo) bf16 pair via truncation; hi+lo ~= f to ~2^-16 rel
__device__ __forceinline__ void split_bf(float f, short& hi, short& lo) {
    union { float f; unsigned u; } v; v.f = f;
    hi = (short)(v.u >> 16);
    union { unsigned u; float f; } h; h.u = v.u & 0xffff0000u;
    float r = f - h.f;
    union { float f; unsigned u; } w; w.f = r;
    lo = (short)(w.u >> 16);
}

__device__ __forceinline__ bf16x8 ldwfrag(const float* __restrict__ W,
                                          int n, int stride, int k0, int kmax) {
    bf16x8 r;
    #pragma unroll
    for (int j = 0; j < 8; ++j) {
        int k = k0 + j;
        float f = (k < kmax) ? W[n * stride + k] : 0.0f;
        r[j] = f2bf_rne(f);
    }
    return r;
}

#define MF(A, B, C) __builtin_amdgcn_mfma_f32_16x16x32_bf16(A, B, C, 0, 0, 0)

// One pipelined timestep. RO: own-layer read base (this iter's read parity),
// RBp: below-layer read base, WR: write base (opposite parity).
#define STEP(TI, RO, RBp, WR) do {                                           \
    const int ti_ = (TI);                                                    \
    const bool act_ = (wg == 0) ? (ti_ < Tt)                                 \
                    : (wg == 1) ? (ti_ >= 1 && ti_ <= Tt)                    \
                                : (ti_ >= 2);                                \
    if (act_) {                                                              \
        f32x4 acc[4];                                                        \
        _Pragma("unroll")                                                    \
        for (int gi = 0; gi < 4; ++gi)                                       \
            acc[gi] = (f32x4){bs[gi], bs[gi], bs[gi], bs[gi]};               \
        if (wg == 0 && kg == 0) {   /* split prefetched x(t) into frags */   \
            _Pragma("unroll")                                                \
            for (int jj = 0; jj < In; ++jj) {                                \
                short h_, l_; split_bf(xr[jj], h_, l_);                      \
                xhi[jj] = h_; xlo[jj] = l_;                                  \
            }                                                                \
        }                                                                    \
        __builtin_amdgcn_s_setprio(1);                                       \
        _Pragma("unroll")                                                    \
        for (int kt = 0; kt < 2; ++kt) {   /* recurrent: h_own(t-1) */       \
            bf16x8 oh = *(const bf16x8*)((RO) + kt * 64);                    \
            bf16x8 ol = *(const bf16x8*)((RO) + HLB + kt * 64);              \
            _Pragma("unroll")                                                \
            for (int gi = 0; gi < 4; ++gi) {                                 \
                acc[gi] = MF(oh, WH[gi][kt], acc[gi]);                       \
                acc[gi] = MF(ol, WH[gi][kt], acc[gi]);                       \
            }                                                                \
        }                                                                    \
        if (wg == 0) {                     /* input: x(t) */                 \
            _Pragma("unroll")                                                \
            for (int gi = 0; gi < 4; ++gi) {                                 \
                acc[gi] = MF(xhi, WI[gi][0], acc[gi]);                       \
                acc[gi] = MF(xlo, WI[gi][0], acc[gi]);                       \
            }                                                                \
        } else {                           /* input: h_below(t) */           \
            _Pragma("unroll")                                                \
            for (int kt = 0; kt < 2; ++kt) {                                 \
                bf16x8 bh = *(const bf16x8*)((RBp) + kt * 64);               \
                bf16x8 bl = *(const bf16x8*)((RBp) + HLB + kt * 64);         \
                _Pragma("unroll")                                            \
                for (int gi = 0; gi < 4; ++gi) {                             \
                    acc[gi] = MF(bh, WI[gi][kt], acc[gi]);                   \
                    acc[gi] = MF(bl, WI[gi][kt], acc[gi]);                   \
                }                                                            \
            }                                                                \
        }                                                                    \
        __builtin_amdgcn_s_setprio(0);                                       \
        if (wg == 0 && kg == 0 && ti_ + 1 < Tt) {   /* prefetch x(t+1) */    \
            _Pragma("unroll")                                                \
            for (int jj = 0; jj < In; ++jj)                                  \
                xr[jj] = x[((size_t)(b0 + col) * Tt + (ti_ + 1)) * In + jj]; \
        }                                                                    \
        _Pragma("unroll")                                                    \
        for (int j = 0; j < 4; ++j) {      /* combine + publish */           \
            float iv = sigm(acc[0][j]);                                      \
            float fv = sigm(acc[1][j]);                                      \
            float gv = tanhc(acc[2][j]);                                     \
            float ov = sigm(acc[3][j]);                                      \
            float cn = fmaf(fv, c[j], iv * gv);                              \
            c[j] = cn;                                                       \
            float hn = ov * tanhc(cn);                                       \
            short hi_, lo_; split_bf(hn, hi_, lo_);                          \
            *(short*)((WR) + j * RB_)       = hi_;                           \
            *(short*)((WR) + HLB + j * RB_) = lo_;                           \
        }                                                                    \
    }                                                                        \
    __syncthreads();                                                         \
} while (0)

__global__ __launch_bounds__(NT, 2) void lstm3_mfma(
    const float* __restrict__ x,
    const float* __restrict__ w_ih0, const float* __restrict__ w_hh0,
    const float* __restrict__ b_ih0, const float* __restrict__ b_hh0,
    const float* __restrict__ w_ih1, const float* __restrict__ w_hh1,
    const float* __restrict__ b_ih1, const float* __restrict__ b_hh1,
    const float* __restrict__ w_ih2, const float* __restrict__ w_hh2,
    const float* __restrict__ b_ih2, const float* __restrict__ b_hh2,
    const float* __restrict__ w_fc,  const float* __restrict__ b_fc,
    float* __restrict__ out)
{
    // [parity PB | layer LB | hi/lo HLB | row RB_] fused h buffer (32 KB)
    __shared__ short hb[2][PB / 2];

    const int tid = threadIdx.x;
    const int l   = tid & 63;
    const int wid = tid >> 6;        // 0..11
    const int wg  = wid >> 2;        // layer group 0..2
    const int w4  = wid & 3;         // wave within layer
    const int ub  = w4 * 16;         // unit base
    const int col = l & 15;          // A-row (batch) / B-col (unit)
    const int kg  = l >> 4;          // k-group 0..3
    const int b0  = blockIdx.x * TBt;

    // ---- zero both parities (pipeline-fill h(t<0)=0) ----
    for (int i = tid; i < PB * 2 / 4; i += NT) ((int*)hb)[i] = 0;

    // ---- per-layer weight selection ----
    const float* whh = (wg == 0) ? w_hh0 : (wg == 1) ? w_hh1 : w_hh2;
    const float* wih = (wg == 0) ? w_ih0 : (wg == 1) ? w_ih1 : w_ih2;
    const float* bih = (wg == 0) ? b_ih0 : (wg == 1) ? b_ih1 : b_ih2;
    const float* bhh = (wg == 0) ? b_hh0 : (wg == 1) ? b_hh1 : b_hh2;

    // ---- weights -> register fragments (once) ----
    bf16x8 WH[4][2], WI[4][2];
    float  bs[4];
    #pragma unroll
    for (int gi = 0; gi < 4; ++gi) {
        int n = gi * 64 + ub + col;
        bs[gi] = bih[n] + bhh[n];
        #pragma unroll
        for (int kt = 0; kt < 2; ++kt) {
            WH[gi][kt] = ldwfrag(whh, n, Hh, kt * 32 + kg * 8, Hh);
            if (wg == 0) {
                WI[gi][kt] = (kt == 0) ? ldwfrag(wih, n, In, kg * 8, In)
                                       : ldwfrag(wih, n, In, 64, 0);
            } else {
                WI[gi][kt] = ldwfrag(wih, n, Hh, kt * 32 + kg * 8, Hh);
            }
        }
    }

    // ---- loop-invariant LDS base pointers ----
    // READ base must include the lane's k-slice: + kg*16 bytes (kg*8 shorts).
    // (r10 BUG: this term was missing -> absmax 1.56e-2.)
    char* hbB = (char*)hb;
    const int lbelow = (wg > 0) ? (wg - 1) : 0;
    const int lown   = (wg > 0) ? LB : 0;       // own = below + LB (wg0: +0)
    const char* rbB_ = hbB + lbelow * LB + col * RB_ + kg * 16;   // parity 0
    const char* rbA_ = rbB_ + PB;                                 // parity 1
    const char* roA  = rbA_ + lown;
    const char* roB  = rbB_ + lown;
    char* wrA = hbB + wg * LB + (kg * 4) * RB_ + (ub + col) * 2;  // parity 0
    char* wrB = wrA + PB;                                         // parity 1

    // ---- x prefetch + persistent input fragments ----
    float xr[5] = {0.f, 0.f, 0.f, 0.f, 0.f};
    bf16x8 xhi, xlo;
    #pragma unroll
    for (int j = 0; j < 8; ++j) { xhi[j] = 0; xlo[j] = 0; }
    if (wg == 0 && kg == 0) {
        #pragma unroll
        for (int j = 0; j < In; ++j)
            xr[j] = x[((size_t)(b0 + col) * Tt + 0) * In + j];
    }

    float c[4] = {0.f, 0.f, 0.f, 0.f};   // cell state (rows kg*4+j, u=ub+col)

    __syncthreads();

    // ---- systolic main loop: 258 iterations, manually 2x unrolled ----
    #pragma unroll 1
    for (int t2 = 0; t2 < Tt + 2; t2 += 2) {
        STEP(t2,     roA, rbA_, wrA);   // reads parity 1, writes parity 0
        STEP(t2 + 1, roB, rbB_, wrB);   // reads parity 0, writes parity 1
    }

    // ---- final FC on h2(T-1): written at ti=Tt+1 -> parity 1 ----
    if (tid < TBt) {
        const int b = tid;
        const char* hp = hbB + PB + 2 * LB + b * RB_;
        float accf = b_fc[0];
        #pragma unroll 1
        for (int u = 0; u < Hh; ++u) {
            unsigned hu = ((unsigned)*(const unsigned short*)(hp + u * 2)) << 16;
            unsigned lu = ((unsigned)*(const unsigned short*)(hp + HLB + u * 2)) << 16;
            union { unsigned u; float f; } A, L2; A.u = hu; L2.u = lu;
            accf = fmaf(A.f + L2.f, w_fc[u], accf);
        }
        out[b0 + b] = accf;
    }
}

extern "C" void kernel_launch(void* const* d_in, const int* in_sizes, int n_in,
                              void* d_out, int out_size, void* d_ws, size_t ws_size,
                              hipStream_t stream) {
    const float* x     = (const float*)d_in[0];
    const float* w_ih0 = (const float*)d_in[1];
    const float* w_hh0 = (const float*)d_in[2];
    const float* b_ih0 = (const float*)d_in[3];
    const float* b_hh0 = (const float*)d_in[4];
    const float* w_ih1 = (const float*)d_in[5];
    const float* w_hh1 = (const float*)d_in[6];
    const float* b_ih1 = (const float*)d_in[7];
    const float* b_hh1 = (const float*)d_in[8];
    const float* w_ih2 = (const float*)d_in[9];
    const float* w_hh2 = (const float*)d_in[10];
    const float* b_ih2 = (const float*)d_in[11];
    const float* b_hh2 = (const float*)d_in[12];
    const float* w_fc  = (const float*)d_in[13];
    const float* b_fc  = (const float*)d_in[14];
    float* out = (float*)d_out;

    lstm3_mfma<<<NB, NT, 0, stream>>>(x,
        w_ih0, w_hh0, b_ih0, b_hh0,
        w_ih1, w_hh1, b_ih1, b_hh1,
        w_ih2, w_hh2, b_ih2, b_hh2,
        w_fc, b_fc, out);
}

// Round 9
// 355.356 us; speedup vs baseline: 8.6974x; 1.5693x over previous
//
#include <hip/hip_runtime.h>
#include <math.h>

// LSTM: I=5, H=64, L=3, O=1, B=1024, T=256, fp32 in/out.
// Round-12: row-scatter -> combine issue scales with real batch.
// r8/r9/r11 POST-MORTEM: issue-bound at ~74% active-CU VALUBusy; per-SIMD
// issue ~3 waves x ~1140 cyc/iter, dominated by the gate-combine's 4
// j-iterations (10 trans @ ~16cyc/wave64 + ~21 VALU each). r9's TBr=4
// spread failed because rows 0..3 all live in kg0's j=0..3 -> full 4-j
// combine still issued (exec-masked lanes pay issue).
// THIS ROUND: C-tile row = kg*4 + j, so rows {0,4,8,12} are j=0 across all
// k-groups. Scatter real batch b -> tile row 4b: every lane's j=0 is a real
// (b=kg, u=ub+col) output; combine = ONE iteration, no masked waste. 4x cut
// in trans+VALU issue. MFMA padded 4x (matrix pipe had ~70% headroom).
// NB=256 (TBr=4) -> 1 block/CU on all 256 CUs.
// Also: bias as C-operand of first MFMA (kills 16 acc-init movs/iter);
// i*g rcp-merge (1-eg)*rcp((1+ei)(1+eg)) - SAFE: |preact| <= ~12
// deterministically (|w|<=0.125, |h|<1, K=64) -> products <= 2^53.
// tanh(cn) keeps saturation-safe form (c unbounded in principle).
// x loads only on col%4==0 lanes (padded A-rows stay zero).
// Kept from r11: fused LDS [parity 16384|layer 4608|hi/lo 2304|row 144],
// imm-offset loop-invariant pointers (incl. the kg*16 read k-slice term!),
// manual 2x parity unroll, persistent x frags, setprio around MFMA.
// Layouts (r8 hw-verified): C/D col=lane&15,row=(lane>>4)*4+reg;
// A row=lane&15, k=(lane>>4)*8+j.
// DO NOT raise launch_bounds min-waves (r5: VGPR cap -> 4.3GB scratch).

typedef __attribute__((ext_vector_type(8))) short bf16x8;
typedef __attribute__((ext_vector_type(4))) float f32x4;

constexpr int Hh  = 64;
constexpr int Tt  = 256;
constexpr int In  = 5;
constexpr int TBr = 4;     // REAL batch rows per block (tile rows 0,4,8,12)
constexpr int NB  = 256;   // blocks (NB*TBr = 1024 = B)
constexpr int NT  = 768;   // threads (12 waves)

// LDS geometry (bytes): one array, immediate-offset addressable.
constexpr int RB_ = 144;    // row stride (72 shorts, bank-spread pad)
constexpr int HLB = 2304;   // hi -> lo offset (16 rows * 144)
constexpr int LB  = 4608;   // layer stride (2 * 2304)
constexpr int PB  = 16384;  // parity stride (13824 used, padded to pow2)

__device__ __forceinline__ float tanhc(float x) {
    // tanh(x) = 2*sigmoid(2x) - 1; saturates correctly, NaN-free
    return fmaf(2.0f, __builtin_amdgcn_rcpf(1.0f + exp2f(-2.885390082f * x)), -1.0f);
}

// fp32 -> bf16 round-to-nearest-even (weights; finite values only)
__device__ __forceinline__ short f2bf_rne(float f) {
    union { float f; unsigned u; } v; v.f = f;
    unsigned r = (v.u + 0x7fffu + ((v.u >> 16) & 1u)) >> 16;
    return (short)r;
}
// fp32 -> (hi,lo) bf16 pair via truncation; hi+lo ~= f to ~2^-16 rel
__device__ __forceinline__ void split_bf(float f, short& hi, short& lo) {
    union { float f; unsigned u; } v; v.f = f;
    hi = (short)(v.u >> 16);
    union { unsigned u; float f; } h; h.u = v.u & 0xffff0000u;
    float r = f - h.f;
    union { float f; unsigned u; } w; w.f = r;
    lo = (short)(w.u >> 16);
}

__device__ __forceinline__ bf16x8 ldwfrag(const float* __restrict__ W,
                                          int n, int stride, int k0, int kmax) {
    bf16x8 r;
    #pragma unroll
    for (int j = 0; j < 8; ++j) {
        int k = k0 + j;
        float f = (k < kmax) ? W[n * stride + k] : 0.0f;
        r[j] = f2bf_rne(f);
    }
    return r;
}

#define MF(A, B, C) __builtin_amdgcn_mfma_f32_16x16x32_bf16(A, B, C, 0, 0, 0)

// One pipelined timestep. RO: own-layer read base (this iter's read parity),
// RBp: below-layer read base, WR: write base (opposite parity).
#define STEP(TI, RO, RBp, WR) do {                                           \
    const int ti_ = (TI);                                                    \
    const bool act_ = (wg == 0) ? (ti_ < Tt)                                 \
                    : (wg == 1) ? (ti_ >= 1 && ti_ <= Tt)                    \
                                : (ti_ >= 2);                                \
    if (act_) {                                                              \
        if (xmask) {   /* split prefetched x(t) into frags */                \
            _Pragma("unroll")                                                \
            for (int jj = 0; jj < In; ++jj) {                                \
                short h_, l_; split_bf(xr[jj], h_, l_);                      \
                xhi[jj] = h_; xlo[jj] = l_;                                  \
            }                                                                \
        }                                                                    \
        f32x4 acc[4];                                                        \
        __builtin_amdgcn_s_setprio(1);                                       \
        {                                                                    \
            bf16x8 oh0 = *(const bf16x8*)(RO);                               \
            bf16x8 ol0 = *(const bf16x8*)((RO) + HLB);                       \
            bf16x8 oh1 = *(const bf16x8*)((RO) + 64);                        \
            bf16x8 ol1 = *(const bf16x8*)((RO) + HLB + 64);                  \
            _Pragma("unroll")                                                \
            for (int gi = 0; gi < 4; ++gi)                                   \
                acc[gi] = MF(oh0, WH[gi][0], bsv[gi]);   /* bias as C */     \
            _Pragma("unroll")                                                \
            for (int gi = 0; gi < 4; ++gi)                                   \
                acc[gi] = MF(ol0, WH[gi][0], acc[gi]);                       \
            _Pragma("unroll")                                                \
            for (int gi = 0; gi < 4; ++gi)                                   \
                acc[gi] = MF(oh1, WH[gi][1], acc[gi]);                       \
            _Pragma("unroll")                                                \
            for (int gi = 0; gi < 4; ++gi)                                   \
                acc[gi] = MF(ol1, WH[gi][1], acc[gi]);                       \
        }                                                                    \
        if (wg == 0) {                     /* input: x(t) */                 \
            _Pragma("unroll")                                                \
            for (int gi = 0; gi < 4; ++gi)                                   \
                acc[gi] = MF(xhi, WI[gi][0], acc[gi]);                       \
            _Pragma("unroll")                                                \
            for (int gi = 0; gi < 4; ++gi)                                   \
                acc[gi] = MF(xlo, WI[gi][0], acc[gi]);                       \
        } else {                           /* input: h_below(t) */           \
            bf16x8 bh0 = *(const bf16x8*)(RBp);                              \
            bf16x8 bl0 = *(const bf16x8*)((RBp) + HLB);                      \
            bf16x8 bh1 = *(const bf16x8*)((RBp) + 64);                       \
            bf16x8 bl1 = *(const bf16x8*)((RBp) + HLB + 64);                 \
            _Pragma("unroll")                                                \
            for (int gi = 0; gi < 4; ++gi)                                   \
                acc[gi] = MF(bh0, WI[gi][0], acc[gi]);                       \
            _Pragma("unroll")                                                \
            for (int gi = 0; gi < 4; ++gi)                                   \
                acc[gi] = MF(bl0, WI[gi][0], acc[gi]);                       \
            _Pragma("unroll")                                                \
            for (int gi = 0; gi < 4; ++gi)                                   \
                acc[gi] = MF(bh1, WI[gi][1], acc[gi]);                       \
            _Pragma("unroll")                                                \
            for (int gi = 0; gi < 4; ++gi)                                   \
                acc[gi] = MF(bl1, WI[gi][1], acc[gi]);                       \
        }                                                                    \
        __builtin_amdgcn_s_setprio(0);                                       \
        if (xmask && ti_ + 1 < Tt) {       /* prefetch x(t+1) */             \
            _Pragma("unroll")                                                \
            for (int jj = 0; jj < In; ++jj)                                  \
                xr[jj] = x[xbase + (size_t)(ti_ + 1) * In + jj];             \
        }                                                                    \
        /* combine, j=0 only: output (b=kg, u=ub+col), all 64 lanes real */  \
        float ei = exp2f(-1.442695041f * acc[0][0]);                         \
        float ef = exp2f(-1.442695041f * acc[1][0]);                         \
        float eg = exp2f(-2.885390082f * acc[2][0]);                         \
        float eo = exp2f(-1.442695041f * acc[3][0]);                         \
        float ig = (1.0f - eg) *                                             \
                   __builtin_amdgcn_rcpf((1.0f + ei) * (1.0f + eg));         \
        float fv = __builtin_amdgcn_rcpf(1.0f + ef);                         \
        float cn = fmaf(fv, c0, ig);                                         \
        c0 = cn;                                                             \
        float ov = __builtin_amdgcn_rcpf(1.0f + eo);                         \
        float hn = ov * tanhc(cn);                                           \
        short hi_, lo_; split_bf(hn, hi_, lo_);                              \
        *(short*)(WR)         = hi_;                                         \
        *(short*)((WR) + HLB) = lo_;                                         \
    }                                                                        \
    __syncthreads();                                                         \
} while (0)

__global__ __launch_bounds__(NT, 2) void lstm3_mfma(
    const float* __restrict__ x,
    const float* __restrict__ w_ih0, const float* __restrict__ w_hh0,
    const float* __restrict__ b_ih0, const float* __restrict__ b_hh0,
    const float* __restrict__ w_ih1, const float* __restrict__ w_hh1,
    const float* __restrict__ b_ih1, const float* __restrict__ b_hh1,
    const float* __restrict__ w_ih2, const float* __restrict__ w_hh2,
    const float* __restrict__ b_ih2, const float* __restrict__ b_hh2,
    const float* __restrict__ w_fc,  const float* __restrict__ b_fc,
    float* __restrict__ out)
{
    // [parity PB | layer LB | hi/lo HLB | row RB_] fused h buffer (32 KB)
    __shared__ short hb[2][PB / 2];

    const int tid = threadIdx.x;
    const int l   = tid & 63;
    const int wid = tid >> 6;        // 0..11
    const int wg  = wid >> 2;        // layer group 0..2
    const int w4  = wid & 3;         // wave within layer
    const int ub  = w4 * 16;         // unit base
    const int col = l & 15;          // A-row / B-col index
    const int kg  = l >> 4;          // k-group 0..3
    const int b0  = blockIdx.x * TBr;

    // ---- zero both parities (pipeline fill + dead rows stay 0) ----
    for (int i = tid; i < PB * 2 / 4; i += NT) ((int*)hb)[i] = 0;

    // ---- per-layer weight selection ----
    const float* whh = (wg == 0) ? w_hh0 : (wg == 1) ? w_hh1 : w_hh2;
    const float* wih = (wg == 0) ? w_ih0 : (wg == 1) ? w_ih1 : w_ih2;
    const float* bih = (wg == 0) ? b_ih0 : (wg == 1) ? b_ih1 : b_ih2;
    const float* bhh = (wg == 0) ? b_hh0 : (wg == 1) ? b_hh1 : b_hh2;

    // ---- weights -> register fragments (once); bias pre-splat as C ----
    bf16x8 WH[4][2], WI[4][2];
    f32x4  bsv[4];
    #pragma unroll
    for (int gi = 0; gi < 4; ++gi) {
        int n = gi * 64 + ub + col;
        float bs_ = bih[n] + bhh[n];
        bsv[gi] = (f32x4){bs_, bs_, bs_, bs_};
        #pragma unroll
        for (int kt = 0; kt < 2; ++kt) {
            WH[gi][kt] = ldwfrag(whh, n, Hh, kt * 32 + kg * 8, Hh);
            if (wg == 0) {
                WI[gi][kt] = (kt == 0) ? ldwfrag(wih, n, In, kg * 8, In)
                                       : ldwfrag(wih, n, In, 64, 0);
            } else {
                WI[gi][kt] = ldwfrag(wih, n, Hh, kt * 32 + kg * 8, Hh);
            }
        }
    }

    // ---- loop-invariant LDS base pointers (read incl. kg*16 k-slice!) ----
    char* hbB = (char*)hb;
    const int lbelow = (wg > 0) ? (wg - 1) : 0;
    const int lown   = (wg > 0) ? LB : 0;       // own = below + LB (wg0: +0)
    const char* rbB_ = hbB + lbelow * LB + col * RB_ + kg * 16;   // parity 0
    const char* rbA_ = rbB_ + PB;                                 // parity 1
    const char* roA  = rbA_ + lown;
    const char* roB  = rbB_ + lown;
    // write: real batch b=kg lives at tile row 4*kg (j=0 slot of kg)
    char* wrA = hbB + wg * LB + (kg * 4) * RB_ + (ub + col) * 2;  // parity 0
    char* wrB = wrA + PB;                                         // parity 1

    // ---- x prefetch: only lanes whose A-row is real (col%4==0) ----
    const bool xmask = (wg == 0) && (kg == 0) && ((col & 3) == 0);
    const size_t xbase = (size_t)(b0 + (col >> 2)) * Tt * In;
    float xr[5] = {0.f, 0.f, 0.f, 0.f, 0.f};
    bf16x8 xhi, xlo;
    #pragma unroll
    for (int j = 0; j < 8; ++j) { xhi[j] = 0; xlo[j] = 0; }
    if (xmask) {
        #pragma unroll
        for (int j = 0; j < In; ++j) xr[j] = x[xbase + j];
    }

    float c0 = 0.f;   // cell state for (b=kg, u=ub+col)

    __syncthreads();

    // ---- systolic main loop: 258 iterations, manually 2x unrolled ----
    #pragma unroll 1
    for (int t2 = 0; t2 < Tt + 2; t2 += 2) {
        STEP(t2,     roA, rbA_, wrA);   // reads parity 1, writes parity 0
        STEP(t2 + 1, roB, rbB_, wrB);   // reads parity 0, writes parity 1
    }

    // ---- final FC on h2(T-1): parity 1, batch b at tile row 4b ----
    if (tid < TBr) {
        const int b = tid;
        const char* hp = hbB + PB + 2 * LB + (4 * b) * RB_;
        float accf = b_fc[0];
        #pragma unroll 1
        for (int u = 0; u < Hh; ++u) {
            unsigned hu = ((unsigned)*(const unsigned short*)(hp + u * 2)) << 16;
            unsigned lu = ((unsigned)*(const unsigned short*)(hp + HLB + u * 2)) << 16;
            union { unsigned u; float f; } A, L2; A.u = hu; L2.u = lu;
            accf = fmaf(A.f + L2.f, w_fc[u], accf);
        }
        out[b0 + b] = accf;
    }
}

extern "C" void kernel_launch(void* const* d_in, const int* in_sizes, int n_in,
                              void* d_out, int out_size, void* d_ws, size_t ws_size,
                              hipStream_t stream) {
    const float* x     = (const float*)d_in[0];
    const float* w_ih0 = (const float*)d_in[1];
    const float* w_hh0 = (const float*)d_in[2];
    const float* b_ih0 = (const float*)d_in[3];
    const float* b_hh0 = (const float*)d_in[4];
    const float* w_ih1 = (const float*)d_in[5];
    const float* w_hh1 = (const float*)d_in[6];
    const float* b_ih1 = (const float*)d_in[7];
    const float* b_hh1 = (const float*)d_in[8];
    const float* w_ih2 = (const float*)d_in[9];
    const float* w_hh2 = (const float*)d_in[10];
    const float* b_ih2 = (const float*)d_in[11];
    const float* b_hh2 = (const float*)d_in[12];
    const float* w_fc  = (const float*)d_in[13];
    const float* b_fc  = (const float*)d_in[14];
    float* out = (float*)d_out;

    lstm3_mfma<<<NB, NT, 0, stream>>>(x,
        w_ih0, w_hh0, b_ih0, b_hh0,
        w_ih1, w_hh1, b_ih1, b_hh1,
        w_ih2, w_hh2, b_ih2, b_hh2,
        w_fc, b_fc, out);
}

// Round 10
// 277.850 us; speedup vs baseline: 11.1235x; 1.2789x over previous
//
#include <hip/hip_runtime.h>
#include <math.h>

// LSTM: I=5, H=64, L=3, O=1, B=1024, T=256, fp32 in/out.
// Round-13: hi-only h (drop split-precision lo path) + no-vmcnt barrier.
// r12 POST-MORTEM (316us, all pipes ~45-50%): per CU-iter ~2940cy; DS is
// top consumer (~80 ds_read_b128 = ~960cy + 318cy conflicts = 44%), driven
// by the hi+lo h split doubling reads/MFMAs. THIS ROUND:
//  - h stored bf16-RNE hi-only: halves h ds_reads (8->4/wave), halves
//    recurrent+below MFMA (32->16/wave), publish = 1 write (was 2+8-op
//    split), LDS 32->17KB. c stays fp32 in regs (exact accumulator);
//    h-quant is per-step input noise ~1.3e-4 rms/preact, f-damped.
//  - fp32 sidecar h2f for the FC: wg2 overwrites each step; FC reads fp32
//    -> kills the only non-averaged quantization term. x keeps hi+lo.
//  - ACCURACY BET: predict absmax 3-7e-4 vs 9.5e-4 threshold. If FAIL:
//    revert to hi-only on BELOW path only (keep recurrent hi+lo).
//  - custom barrier: s_waitcnt lgkmcnt(0); s_barrier (no vmcnt drain ->
//    x prefetch latency no longer serializes into every iteration).
// Kept from r12: row-scatter (real batch b -> tile row 4b, combine = 1 j,
// all 64 lanes real), NB=256/TBr=4 (all CUs), bias as C-operand, rcp-merged
// i*g, fused imm-offset LDS w/ loop-invariant pointers (incl kg*16 k-slice
// term), manual 2x parity unroll, persistent x frags, setprio.
// Layouts (r8 hw-verified): C/D col=lane&15,row=(lane>>4)*4+reg;
// A row=lane&15, k=(lane>>4)*8+j.
// DO NOT raise launch_bounds min-waves (r5: VGPR cap -> 4.3GB scratch).

typedef __attribute__((ext_vector_type(8))) short bf16x8;
typedef __attribute__((ext_vector_type(4))) float f32x4;

constexpr int Hh  = 64;
constexpr int Tt  = 256;
constexpr int In  = 5;
constexpr int TBr = 4;     // REAL batch rows per block (tile rows 0,4,8,12)
constexpr int NB  = 256;   // blocks (NB*TBr = 1024 = B)
constexpr int NT  = 768;   // threads (12 waves)

// LDS geometry (bytes), hi-only: one array, immediate-offset addressable.
constexpr int RB_ = 144;    // row stride (72 shorts, bank-spread pad)
constexpr int LB  = 2304;   // layer stride (16 rows * 144)
constexpr int PB  = 8192;   // parity stride (6912 used, padded to pow2)

__device__ __forceinline__ float tanhc(float x) {
    // tanh(x) = 2*sigmoid(2x) - 1; saturates correctly, NaN-free
    return fmaf(2.0f, __builtin_amdgcn_rcpf(1.0f + exp2f(-2.885390082f * x)), -1.0f);
}

// fp32 -> bf16 round-to-nearest-even (finite values only)
__device__ __forceinline__ short f2bf_rne(float f) {
    union { float f; unsigned u; } v; v.f = f;
    unsigned r = (v.u + 0x7fffu + ((v.u >> 16) & 1u)) >> 16;
    return (short)r;
}
// fp32 -> (hi,lo) bf16 pair via truncation; hi+lo ~= f to ~2^-16 rel (x only)
__device__ __forceinline__ void split_bf(float f, short& hi, short& lo) {
    union { float f; unsigned u; } v; v.f = f;
    hi = (short)(v.u >> 16);
    union { unsigned u; float f; } h; h.u = v.u & 0xffff0000u;
    float r = f - h.f;
    union { float f; unsigned u; } w; w.f = r;
    lo = (short)(w.u >> 16);
}

__device__ __forceinline__ bf16x8 ldwfrag(const float* __restrict__ W,
                                          int n, int stride, int k0, int kmax) {
    bf16x8 r;
    #pragma unroll
    for (int j = 0; j < 8; ++j) {
        int k = k0 + j;
        float f = (k < kmax) ? W[n * stride + k] : 0.0f;
        r[j] = f2bf_rne(f);
    }
    return r;
}

#define MF(A, B, C) __builtin_amdgcn_mfma_f32_16x16x32_bf16(A, B, C, 0, 0, 0)

// Barrier: drain LDS ops only (writes visible), skip vmcnt (x load stays in
// flight; compiler waits vmcnt at the use point next iteration).
#define LBAR() asm volatile("s_waitcnt lgkmcnt(0)\n\ts_barrier" ::: "memory")

// One pipelined timestep. RO: own-layer read base (this iter's read parity),
// RBp: below-layer read base, WR: write base (opposite parity).
#define STEP(TI, RO, RBp, WR) do {                                           \
    const int ti_ = (TI);                                                    \
    const bool act_ = (wg == 0) ? (ti_ < Tt)                                 \
                    : (wg == 1) ? (ti_ >= 1 && ti_ <= Tt)                    \
                                : (ti_ >= 2);                                \
    if (act_) {                                                              \
        if (xmask) {   /* split prefetched x(t) into frags */                \
            _Pragma("unroll")                                                \
            for (int jj = 0; jj < In; ++jj) {                                \
                short h_, l_; split_bf(xr[jj], h_, l_);                      \
                xhi[jj] = h_; xlo[jj] = l_;                                  \
            }                                                                \
        }                                                                    \
        f32x4 acc[4];                                                        \
        __builtin_amdgcn_s_setprio(1);                                       \
        {                                                                    \
            bf16x8 oh0 = *(const bf16x8*)(RO);                               \
            bf16x8 oh1 = *(const bf16x8*)((RO) + 64);                        \
            _Pragma("unroll")                                                \
            for (int gi = 0; gi < 4; ++gi)                                   \
                acc[gi] = MF(oh0, WH[gi][0], bsv[gi]);   /* bias as C */     \
            _Pragma("unroll")                                                \
            for (int gi = 0; gi < 4; ++gi)                                   \
                acc[gi] = MF(oh1, WH[gi][1], acc[gi]);                       \
        }                                                                    \
        if (wg == 0) {                     /* input: x(t), hi+lo */          \
            _Pragma("unroll")                                                \
            for (int gi = 0; gi < 4; ++gi)                                   \
                acc[gi] = MF(xhi, WI[gi][0], acc[gi]);                       \
            _Pragma("unroll")                                                \
            for (int gi = 0; gi < 4; ++gi)                                   \
                acc[gi] = MF(xlo, WI[gi][0], acc[gi]);                       \
        } else {                           /* input: h_below(t), hi-only */  \
            bf16x8 bh0 = *(const bf16x8*)(RBp);                              \
            bf16x8 bh1 = *(const bf16x8*)((RBp) + 64);                       \
            _Pragma("unroll")                                                \
            for (int gi = 0; gi < 4; ++gi)                                   \
                acc[gi] = MF(bh0, WI[gi][0], acc[gi]);                       \
            _Pragma("unroll")                                                \
            for (int gi = 0; gi < 4; ++gi)                                   \
                acc[gi] = MF(bh1, WI[gi][1], acc[gi]);                       \
        }                                                                    \
        __builtin_amdgcn_s_setprio(0);                                       \
        if (xmask && ti_ + 1 < Tt) {       /* prefetch x(t+1) */             \
            _Pragma("unroll")                                                \
            for (int jj = 0; jj < In; ++jj)                                  \
                xr[jj] = x[xbase + (size_t)(ti_ + 1) * In + jj];             \
        }                                                                    \
        /* combine, j=0 only: output (b=kg, u=ub+col), all 64 lanes real */  \
        float ei = exp2f(-1.442695041f * acc[0][0]);                         \
        float ef = exp2f(-1.442695041f * acc[1][0]);                         \
        float eg = exp2f(-2.885390082f * acc[2][0]);                         \
        float eo = exp2f(-1.442695041f * acc[3][0]);                         \
        float ig = (1.0f - eg) *                                             \
                   __builtin_amdgcn_rcpf((1.0f + ei) * (1.0f + eg));         \
        float fv = __builtin_amdgcn_rcpf(1.0f + ef);                         \
        float cn = fmaf(fv, c0, ig);                                         \
        c0 = cn;                                                             \
        float ov = __builtin_amdgcn_rcpf(1.0f + eo);                         \
        float hn = ov * tanhc(cn);                                           \
        *(short*)(WR) = f2bf_rne(hn);                                        \
        if (wg == 2) h2f[kg][ub + col] = hn;   /* fp32 sidecar for FC */     \
    }                                                                        \
    LBAR();                                                                  \
} while (0)

__global__ __launch_bounds__(NT, 2) void lstm3_mfma(
    const float* __restrict__ x,
    const float* __restrict__ w_ih0, const float* __restrict__ w_hh0,
    const float* __restrict__ b_ih0, const float* __restrict__ b_hh0,
    const float* __restrict__ w_ih1, const float* __restrict__ w_hh1,
    const float* __restrict__ b_ih1, const float* __restrict__ b_hh1,
    const float* __restrict__ w_ih2, const float* __restrict__ w_hh2,
    const float* __restrict__ b_ih2, const float* __restrict__ b_hh2,
    const float* __restrict__ w_fc,  const float* __restrict__ b_fc,
    float* __restrict__ out)
{
    // [parity PB | layer LB | row RB_] fused hi-only h buffer (16 KB)
    __shared__ short hb[2][PB / 2];
    __shared__ float h2f[TBr][Hh];      // fp32 h2 sidecar (1 KB)

    const int tid = threadIdx.x;
    const int l   = tid & 63;
    const int wid = tid >> 6;        // 0..11
    const int wg  = wid >> 2;        // layer group 0..2
    const int w4  = wid & 3;         // wave within layer
    const int ub  = w4 * 16;         // unit base
    const int col = l & 15;          // A-row / B-col index
    const int kg  = l >> 4;          // k-group 0..3
    const int b0  = blockIdx.x * TBr;

    // ---- zero both parities (pipeline fill + dead rows stay 0) ----
    for (int i = tid; i < PB * 2 / 4; i += NT) ((int*)hb)[i] = 0;

    // ---- per-layer weight selection ----
    const float* whh = (wg == 0) ? w_hh0 : (wg == 1) ? w_hh1 : w_hh2;
    const float* wih = (wg == 0) ? w_ih0 : (wg == 1) ? w_ih1 : w_ih2;
    const float* bih = (wg == 0) ? b_ih0 : (wg == 1) ? b_ih1 : b_ih2;
    const float* bhh = (wg == 0) ? b_hh0 : (wg == 1) ? b_hh1 : b_hh2;

    // ---- weights -> register fragments (once); bias pre-splat as C ----
    bf16x8 WH[4][2], WI[4][2];
    f32x4  bsv[4];
    #pragma unroll
    for (int gi = 0; gi < 4; ++gi) {
        int n = gi * 64 + ub + col;
        float bs_ = bih[n] + bhh[n];
        bsv[gi] = (f32x4){bs_, bs_, bs_, bs_};
        #pragma unroll
        for (int kt = 0; kt < 2; ++kt) {
            WH[gi][kt] = ldwfrag(whh, n, Hh, kt * 32 + kg * 8, Hh);
            if (wg == 0) {
                WI[gi][kt] = (kt == 0) ? ldwfrag(wih, n, In, kg * 8, In)
                                       : ldwfrag(wih, n, In, 64, 0);
            } else {
                WI[gi][kt] = ldwfrag(wih, n, Hh, kt * 32 + kg * 8, Hh);
            }
        }
    }

    // ---- loop-invariant LDS base pointers (read incl. kg*16 k-slice!) ----
    char* hbB = (char*)hb;
    const int lbelow = (wg > 0) ? (wg - 1) : 0;
    const int lown   = (wg > 0) ? LB : 0;       // own = below + LB (wg0: +0)
    const char* rbB_ = hbB + lbelow * LB + col * RB_ + kg * 16;   // parity 0
    const char* rbA_ = rbB_ + PB;                                 // parity 1
    const char* roA  = rbA_ + lown;
    const char* roB  = rbB_ + lown;
    // write: real batch b=kg lives at tile row 4*kg (j=0 slot of kg)
    char* wrA = hbB + wg * LB + (kg * 4) * RB_ + (ub + col) * 2;  // parity 0
    char* wrB = wrA + PB;                                         // parity 1

    // ---- x prefetch: only lanes whose A-row is real (col%4==0) ----
    const bool xmask = (wg == 0) && (kg == 0) && ((col & 3) == 0);
    const size_t xbase = (size_t)(b0 + (col >> 2)) * Tt * In;
    float xr[5] = {0.f, 0.f, 0.f, 0.f, 0.f};
    bf16x8 xhi, xlo;
    #pragma unroll
    for (int j = 0; j < 8; ++j) { xhi[j] = 0; xlo[j] = 0; }
    if (xmask) {
        #pragma unroll
        for (int j = 0; j < In; ++j) xr[j] = x[xbase + j];
    }

    float c0 = 0.f;   // cell state for (b=kg, u=ub+col)

    __syncthreads();

    // ---- systolic main loop: 258 iterations, manually 2x unrolled ----
    #pragma unroll 1
    for (int t2 = 0; t2 < Tt + 2; t2 += 2) {
        STEP(t2,     roA, rbA_, wrA);   // reads parity 1, writes parity 0
        STEP(t2 + 1, roB, rbB_, wrB);   // reads parity 0, writes parity 1
    }

    // ---- final FC on h2(T-1) from the fp32 sidecar ----
    if (tid < TBr) {
        const int b = tid;
        float accf = b_fc[0];
        #pragma unroll 1
        for (int u = 0; u < Hh; ++u)
            accf = fmaf(h2f[b][u], w_fc[u], accf);
        out[b0 + b] = accf;
    }
}

extern "C" void kernel_launch(void* const* d_in, const int* in_sizes, int n_in,
                              void* d_out, int out_size, void* d_ws, size_t ws_size,
                              hipStream_t stream) {
    const float* x     = (const float*)d_in[0];
    const float* w_ih0 = (const float*)d_in[1];
    const float* w_hh0 = (const float*)d_in[2];
    const float* b_ih0 = (const float*)d_in[3];
    const float* b_hh0 = (const float*)d_in[4];
    const float* w_ih1 = (const float*)d_in[5];
    const float* w_hh1 = (const float*)d_in[6];
    const float* b_ih1 = (const float*)d_in[7];
    const float* b_hh1 = (const float*)d_in[8];
    const float* w_ih2 = (const float*)d_in[9];
    const float* w_hh2 = (const float*)d_in[10];
    const float* b_ih2 = (const float*)d_in[11];
    const float* b_hh2 = (const float*)d_in[12];
    const float* w_fc  = (const float*)d_in[13];
    const float* b_fc  = (const float*)d_in[14];
    float* out = (float*)d_out;

    lstm3_mfma<<<NB, NT, 0, stream>>>(x,
        w_ih0, w_hh0, b_ih0, b_hh0,
        w_ih1, w_hh1, b_ih1, b_hh1,
        w_ih2, w_hh2, b_ih2, b_hh2,
        w_fc, b_fc, out);
}